// Round 1
// baseline (2310.332 us; speedup 1.0000x reference)
//
#include <hip/hip_runtime.h>
#include <hip/hip_bf16.h>
#include <math.h>

// Problem constants
#define B_  4
#define L_  512
#define H_  1024
#define M_  128
#define E_  64
#define NH_ 16
#define R_  1024
#define D_  768
#define BLK_ 64
#define C_  97
#define NROW (B_*R_)          // 4096
#define KB_  (D_/BLK_)        // 12

// ---------------------------------------------------------------------------
// Kernel 1: entity pooling (segment logsumexp over mentions + mean attention)
// grid = B*E blocks, 256 threads
// ---------------------------------------------------------------------------
__global__ __launch_bounds__(256) void pool_kernel(
    const float* __restrict__ ent_lhs,     // [B,M,H]
    const float* __restrict__ attn,        // [B,NH,M,L]
    const int*   __restrict__ labels,      // [B,M]
    float* __restrict__ ent_emb,           // [B,E,H]
    float* __restrict__ ent_attn)          // [B,E,NH,L]
{
    int be = blockIdx.x;            // b*E + e
    int b  = be >> 6;               // E=64
    int e  = be & 63;

    __shared__ int midx[M_];
    __shared__ int scnt;
    if (threadIdx.x == 0) scnt = 0;
    __syncthreads();
    if (threadIdx.x < M_) {
        if (labels[b*M_ + threadIdx.x] == e) {
            int p = atomicAdd(&scnt, 1);
            midx[p] = threadIdx.x;
        }
    }
    __syncthreads();
    int cnt = scnt;

    // ent_emb: logsumexp over the cnt mentions, per h
    for (int h = threadIdx.x; h < H_; h += blockDim.x) {
        float r = 0.f;
        if (cnt > 0) {
            const float* base = ent_lhs + (size_t)b*M_*H_ + h;
            float mx = -INFINITY;
            for (int k = 0; k < cnt; ++k) mx = fmaxf(mx, base[(size_t)midx[k]*H_]);
            float s = 0.f;
            for (int k = 0; k < cnt; ++k) s += expf(base[(size_t)midx[k]*H_] - mx);
            r = mx + logf(s);
        }
        ent_emb[(size_t)be*H_ + h] = r;
    }

    // ent_attn: mean over mentions
    float inv = (cnt > 0) ? 1.f/(float)cnt : 0.f;
    for (int x = threadIdx.x; x < NH_*L_; x += blockDim.x) {
        int nh = x >> 9;            // L=512
        int l  = x & (L_-1);
        const float* base = attn + (((size_t)b*NH_ + nh)*M_)*L_ + l;
        float s = 0.f;
        for (int k = 0; k < cnt; ++k) s += base[(size_t)midx[k]*L_];
        ent_attn[((size_t)be*NH_ + nh)*L_ + l] = s * inv;
    }
}

// ---------------------------------------------------------------------------
// Kernel 2: pair attention: ht_attn[b,r,l] = mean_nh(h_attn*t_attn), normalized
// grid = B*R blocks, 256 threads (each thread 2 l's)
// ---------------------------------------------------------------------------
__global__ __launch_bounds__(256) void pair_attn_kernel(
    const float* __restrict__ ent_attn,    // [B,E,NH,L]
    const int*   __restrict__ hts,         // [B,R,2]
    float* __restrict__ ht_attn)           // [B,R,L]
{
    int br = blockIdx.x;            // b*R + r
    int b  = br >> 10;              // R=1024
    int hi = hts[br*2 + 0];
    int ti = hts[br*2 + 1];
    const float* ph = ent_attn + ((size_t)(b*E_ + hi)*NH_)*L_;
    const float* pt = ent_attn + ((size_t)(b*E_ + ti)*NH_)*L_;

    float v[2];
    float part = 0.f;
    #pragma unroll
    for (int q = 0; q < 2; ++q) {
        int l = threadIdx.x + q*256;
        float s = 0.f;
        #pragma unroll
        for (int nh = 0; nh < NH_; ++nh) s += ph[nh*L_ + l] * pt[nh*L_ + l];
        v[q] = s * (1.f/(float)NH_);
        part += v[q];
    }
    // block reduce
    __shared__ float red[4];
    #pragma unroll
    for (int off = 32; off > 0; off >>= 1) part += __shfl_down(part, off, 64);
    if ((threadIdx.x & 63) == 0) red[threadIdx.x >> 6] = part;
    __syncthreads();
    float tot = red[0] + red[1] + red[2] + red[3];
    float norm = 1.f / (tot + 1e-5f);
    #pragma unroll
    for (int q = 0; q < 2; ++q) {
        int l = threadIdx.x + q*256;
        ht_attn[(size_t)br*L_ + l] = v[q] * norm;
    }
}

// ---------------------------------------------------------------------------
// Kernel 3: rel = ht_attn @ seq_lhs per batch. [1024x512]@[512x1024]
// 128x128 tile, BK=16, 8x8 micro. grid (8,8,4), 256 thr
// ---------------------------------------------------------------------------
__global__ __launch_bounds__(256) void gemm_rel(
    const float* __restrict__ ht_attn,     // [B,R,L]
    const float* __restrict__ seq,         // [B,L,H]
    float* __restrict__ rel)               // [B,R,H]
{
    int b = blockIdx.z;
    const float* A  = ht_attn + (size_t)b*R_*L_;
    const float* Bm = seq     + (size_t)b*L_*H_;
    float*       C  = rel     + (size_t)b*R_*H_;
    int row0 = blockIdx.y * 128, col0 = blockIdx.x * 128;

    __shared__ float As[16][132];   // [k][row], +4 pad (bank + alignment)
    __shared__ float Bs[16][128];   // [k][col]
    float acc[8][8] = {};
    int tx = threadIdx.x & 15, ty = threadIdx.x >> 4;

    for (int k0 = 0; k0 < L_; k0 += 16) {
        for (int e = threadIdx.x; e < 2048; e += 256) {
            int r = e >> 4, k = e & 15;
            As[k][r] = A[(size_t)(row0 + r)*L_ + k0 + k];
        }
        for (int e = threadIdx.x; e < 2048; e += 256) {
            int k = e >> 7, c = e & 127;
            Bs[k][c] = Bm[(size_t)(k0 + k)*H_ + col0 + c];
        }
        __syncthreads();
        #pragma unroll
        for (int k = 0; k < 16; ++k) {
            float a[8], bv[8];
            #pragma unroll
            for (int i = 0; i < 8; ++i) a[i] = As[k][ty*8 + i];
            #pragma unroll
            for (int j = 0; j < 8; ++j) bv[j] = Bs[k][tx*8 + j];
            #pragma unroll
            for (int i = 0; i < 8; ++i)
                #pragma unroll
                for (int j = 0; j < 8; ++j) acc[i][j] += a[i]*bv[j];
        }
        __syncthreads();
    }
    #pragma unroll
    for (int i = 0; i < 8; ++i)
        #pragma unroll
        for (int j = 0; j < 8; ++j)
            C[(size_t)(row0 + ty*8 + i)*H_ + col0 + tx*8 + j] = acc[i][j];
}

// ---------------------------------------------------------------------------
// Kernel 4: extractor GEMM with fused gather + bias + tanh.
// hv[n,d] = tanh( sum_k hcat[n,k]*W[k,d] + bias[d] ),
// hcat[n,k] = k<1024 ? ent_emb[b, hts[n,which], k] : rel[n, k-1024]
// M=4096, N=768, K=2048. 128x128 tile BK=16, 8x8 micro. grid (6,32)
// ---------------------------------------------------------------------------
__global__ __launch_bounds__(256) void gemm_ext(
    const float* __restrict__ ent_emb,     // [B,E,H]
    const float* __restrict__ rel,         // [B*R, H]
    const int*   __restrict__ hts,         // [B*R, 2]
    int which,
    const float* __restrict__ W,           // [2H, D]
    const float* __restrict__ bias,        // [D]
    float* __restrict__ outv)              // [B*R, D]
{
    int row0 = blockIdx.y * 128, col0 = blockIdx.x * 128;
    __shared__ float As[16][132];
    __shared__ float Bs[16][128];
    __shared__ const float* rowbase[128];
    int tx = threadIdx.x & 15, ty = threadIdx.x >> 4;

    if (threadIdx.x < 128) {
        int n = row0 + threadIdx.x;
        int b = n >> 10;            // R=1024
        int idx = hts[n*2 + which];
        rowbase[threadIdx.x] = ent_emb + (size_t)(b*E_ + idx)*H_;
    }
    __syncthreads();

    float acc[8][8] = {};
    for (int k0 = 0; k0 < 2*H_; k0 += 16) {
        if (k0 < H_) {
            for (int e = threadIdx.x; e < 2048; e += 256) {
                int r = e >> 4, k = e & 15;
                As[k][r] = rowbase[r][k0 + k];
            }
        } else {
            for (int e = threadIdx.x; e < 2048; e += 256) {
                int r = e >> 4, k = e & 15;
                As[k][r] = rel[(size_t)(row0 + r)*H_ + (k0 - H_) + k];
            }
        }
        for (int e = threadIdx.x; e < 2048; e += 256) {
            int k = e >> 7, c = e & 127;
            Bs[k][c] = W[(size_t)(k0 + k)*D_ + col0 + c];
        }
        __syncthreads();
        #pragma unroll
        for (int k = 0; k < 16; ++k) {
            float a[8], bv[8];
            #pragma unroll
            for (int i = 0; i < 8; ++i) a[i] = As[k][ty*8 + i];
            #pragma unroll
            for (int j = 0; j < 8; ++j) bv[j] = Bs[k][tx*8 + j];
            #pragma unroll
            for (int i = 0; i < 8; ++i)
                #pragma unroll
                for (int j = 0; j < 8; ++j) acc[i][j] += a[i]*bv[j];
        }
        __syncthreads();
    }
    #pragma unroll
    for (int i = 0; i < 8; ++i) {
        int n = row0 + ty*8 + i;
        #pragma unroll
        for (int j = 0; j < 8; ++j) {
            int d = col0 + tx*8 + j;
            outv[(size_t)n*D_ + d] = tanhf(acc[i][j] + bias[d]);
        }
    }
}

// ---------------------------------------------------------------------------
// Kernel 5a: init output with bias
// ---------------------------------------------------------------------------
__global__ void out_init(const float* __restrict__ bb, float* __restrict__ out)
{
    int i = blockIdx.x*256 + threadIdx.x;
    if (i < NROW*C_) out[i] = bb[i % C_];
}

// ---------------------------------------------------------------------------
// Kernel 5b: fused block-bilinear classifier, split-K over kb with atomics.
// out[n,c] += sum_{i,j} hv[n,kb*64+i]*tv[n,kb*64+j]*Wb[(kb*4096+i*64+j)*97+c]
// grid (12 kb, 64 rowtiles), 256 thr. 64 rows x 97(->128) cols per block.
// ---------------------------------------------------------------------------
__global__ __launch_bounds__(256) void final_kernel(
    const float* __restrict__ hv,          // [4096, 768]
    const float* __restrict__ tv,          // [4096, 768]
    const float* __restrict__ Wb,          // [49152, 97]
    float* __restrict__ out)               // [4096, 97]
{
    int kb   = blockIdx.x;        // 0..11
    int row0 = blockIdx.y * 64;
    __shared__ float hvS[64][65];
    __shared__ float tvS[64][65];
    __shared__ float Ws[64][128]; // [j][c], cols 97..127 unused garbage
    int tx = threadIdx.x & 15, ty = threadIdx.x >> 4;   // tx: 8-col group, ty: 4-row group

    for (int e = threadIdx.x; e < 4096; e += 256) {
        int r = e >> 6, c = e & 63;
        hvS[r][c] = hv[(size_t)(row0 + r)*D_ + kb*BLK_ + c];
        tvS[r][c] = tv[(size_t)(row0 + r)*D_ + kb*BLK_ + c];
    }

    float acc[4][8] = {};
    const float* wbase = Wb + (size_t)kb*BLK_*BLK_*C_;
    for (int i = 0; i < BLK_; ++i) {
        __syncthreads();   // protects Ws reuse (and covers hv/tv staging at i=0)
        const float* wsrc = wbase + (size_t)i*BLK_*C_;
        for (int e = threadIdx.x; e < BLK_*C_; e += 256) {
            int j = e / C_;
            int c = e - j*C_;
            Ws[j][c] = wsrc[e];
        }
        __syncthreads();

        float ah[4];
        #pragma unroll
        for (int rr = 0; rr < 4; ++rr) ah[rr] = hvS[ty*4+rr][i];

        #pragma unroll 4
        for (int j = 0; j < BLK_; ++j) {
            float w[8];
            #pragma unroll
            for (int cc = 0; cc < 8; ++cc) w[cc] = Ws[j][tx*8 + cc];
            #pragma unroll
            for (int rr = 0; rr < 4; ++rr) {
                float p = ah[rr] * tvS[ty*4+rr][j];
                #pragma unroll
                for (int cc = 0; cc < 8; ++cc) acc[rr][cc] += p * w[cc];
            }
        }
    }

    #pragma unroll
    for (int rr = 0; rr < 4; ++rr) {
        int n = row0 + ty*4 + rr;
        #pragma unroll
        for (int cc = 0; cc < 8; ++cc) {
            int c = tx*8 + cc;
            if (c < C_) atomicAdd(&out[(size_t)n*C_ + c], acc[rr][cc]);
        }
    }
}

// ---------------------------------------------------------------------------
extern "C" void kernel_launch(void* const* d_in, const int* in_sizes, int n_in,
                              void* d_out, int out_size, void* d_ws, size_t ws_size,
                              hipStream_t stream)
{
    const float* seq_lhs = (const float*)d_in[0];
    const float* ent_lhs = (const float*)d_in[1];
    const float* attn    = (const float*)d_in[2];
    const int*   labels  = (const int*)d_in[3];
    const int*   hts     = (const int*)d_in[4];
    const float* Wh      = (const float*)d_in[5];
    const float* bh      = (const float*)d_in[6];
    const float* Wt      = (const float*)d_in[7];
    const float* bt      = (const float*)d_in[8];
    const float* Wb      = (const float*)d_in[9];
    const float* bb      = (const float*)d_in[10];
    float* out = (float*)d_out;

    float* ws       = (float*)d_ws;
    float* ent_emb  = ws;                       // B*E*H      = 262144
    float* ent_attn = ent_emb  + 262144;        // B*E*NH*L   = 2097152
    float* ht_attn  = ent_attn + 2097152;       // B*R*L      = 2097152
    float* rel      = ht_attn  + 2097152;       // B*R*H      = 4194304
    float* hv       = rel      + 4194304;       // B*R*D      = 3145728
    float* tv       = hv       + 3145728;       // B*R*D      = 3145728
    // total: 14942208 floats = 59.77 MB

    pool_kernel<<<B_*E_, 256, 0, stream>>>(ent_lhs, attn, labels, ent_emb, ent_attn);
    pair_attn_kernel<<<B_*R_, 256, 0, stream>>>(ent_attn, hts, ht_attn);
    gemm_rel<<<dim3(H_/128, R_/128, B_), 256, 0, stream>>>(ht_attn, seq_lhs, rel);
    gemm_ext<<<dim3(D_/128, NROW/128), 256, 0, stream>>>(ent_emb, rel, hts, 0, Wh, bh, hv);
    gemm_ext<<<dim3(D_/128, NROW/128), 256, 0, stream>>>(ent_emb, rel, hts, 1, Wt, bt, tv);
    out_init<<<(NROW*C_ + 255)/256, 256, 0, stream>>>(bb, out);
    final_kernel<<<dim3(KB_, NROW/64), 256, 0, stream>>>(hv, tv, Wb, out);
}

// Round 2
// 578.502 us; speedup vs baseline: 3.9936x; 3.9936x over previous
//
#include <hip/hip_runtime.h>
#include <hip/hip_bf16.h>
#include <math.h>

// Problem constants
#define B_  4
#define L_  512
#define H_  1024
#define M_  128
#define E_  64
#define NH_ 16
#define R_  1024
#define D_  768
#define BLK_ 64
#define C_  97
#define NROW (B_*R_)          // 4096
#define KB_  (D_/BLK_)        // 12

typedef __attribute__((ext_vector_type(8))) unsigned short ushort8;
typedef __attribute__((ext_vector_type(8))) short s8;       // 8 bf16 MFMA operand
typedef __attribute__((ext_vector_type(4))) float f4;       // MFMA C/D

__device__ __forceinline__ unsigned short f2bf(float x) {   // RNE f32->bf16
    unsigned u = __builtin_bit_cast(unsigned, x);
    unsigned r = (u + 0x7fffu + ((u >> 16) & 1u)) >> 16;
    return (unsigned short)r;
}
__device__ __forceinline__ float bf2f(unsigned short h) {
    unsigned u = ((unsigned)h) << 16;
    return __builtin_bit_cast(float, u);
}

// ---------------------------------------------------------------------------
// Kernel 1: entity pooling (unchanged from R1, verified)
// ---------------------------------------------------------------------------
__global__ __launch_bounds__(256) void pool_kernel(
    const float* __restrict__ ent_lhs, const float* __restrict__ attn,
    const int* __restrict__ labels,
    float* __restrict__ ent_emb, float* __restrict__ ent_attn)
{
    int be = blockIdx.x, b = be >> 6, e = be & 63;
    __shared__ int midx[M_];
    __shared__ int scnt;
    if (threadIdx.x == 0) scnt = 0;
    __syncthreads();
    if (threadIdx.x < M_) {
        if (labels[b*M_ + threadIdx.x] == e) {
            int p = atomicAdd(&scnt, 1);
            midx[p] = threadIdx.x;
        }
    }
    __syncthreads();
    int cnt = scnt;
    for (int h = threadIdx.x; h < H_; h += blockDim.x) {
        float r = 0.f;
        if (cnt > 0) {
            const float* base = ent_lhs + (size_t)b*M_*H_ + h;
            float mx = -INFINITY;
            for (int k = 0; k < cnt; ++k) mx = fmaxf(mx, base[(size_t)midx[k]*H_]);
            float s = 0.f;
            for (int k = 0; k < cnt; ++k) s += expf(base[(size_t)midx[k]*H_] - mx);
            r = mx + logf(s);
        }
        ent_emb[(size_t)be*H_ + h] = r;
    }
    float inv = (cnt > 0) ? 1.f/(float)cnt : 0.f;
    for (int x = threadIdx.x; x < NH_*L_; x += blockDim.x) {
        int nh = x >> 9, l = x & (L_-1);
        const float* base = attn + (((size_t)b*NH_ + nh)*M_)*L_ + l;
        float s = 0.f;
        for (int k = 0; k < cnt; ++k) s += base[(size_t)midx[k]*L_];
        ent_attn[((size_t)be*NH_ + nh)*L_ + l] = s * inv;
    }
}

// ---------------------------------------------------------------------------
// Kernel 2: pair attention (unchanged from R1, verified)
// ---------------------------------------------------------------------------
__global__ __launch_bounds__(256) void pair_attn_kernel(
    const float* __restrict__ ent_attn, const int* __restrict__ hts,
    float* __restrict__ ht_attn)
{
    int br = blockIdx.x, b = br >> 10;
    int hi = hts[br*2 + 0], ti = hts[br*2 + 1];
    const float* ph = ent_attn + ((size_t)(b*E_ + hi)*NH_)*L_;
    const float* pt = ent_attn + ((size_t)(b*E_ + ti)*NH_)*L_;
    float v[2], part = 0.f;
    #pragma unroll
    for (int q = 0; q < 2; ++q) {
        int l = threadIdx.x + q*256;
        float s = 0.f;
        #pragma unroll
        for (int nh = 0; nh < NH_; ++nh) s += ph[nh*L_ + l] * pt[nh*L_ + l];
        v[q] = s * (1.f/(float)NH_);
        part += v[q];
    }
    __shared__ float red[4];
    #pragma unroll
    for (int off = 32; off > 0; off >>= 1) part += __shfl_down(part, off, 64);
    if ((threadIdx.x & 63) == 0) red[threadIdx.x >> 6] = part;
    __syncthreads();
    float norm = 1.f / (red[0] + red[1] + red[2] + red[3] + 1e-5f);
    #pragma unroll
    for (int q = 0; q < 2; ++q)
        ht_attn[(size_t)br*L_ + threadIdx.x + q*256] = v[q] * norm;
}

// ---------------------------------------------------------------------------
// Prep: elementwise f32 -> bf16 (ht_attn)
// ---------------------------------------------------------------------------
__global__ __launch_bounds__(256) void cvt_ht(const float* __restrict__ in,
                                              unsigned short* __restrict__ outp)
{
    size_t idx = ((size_t)blockIdx.x*256 + threadIdx.x)*8;
    float4 x0 = *(const float4*)(in + idx);
    float4 x1 = *(const float4*)(in + idx + 4);
    ushort8 o;
    o[0]=f2bf(x0.x); o[1]=f2bf(x0.y); o[2]=f2bf(x0.z); o[3]=f2bf(x0.w);
    o[4]=f2bf(x1.x); o[5]=f2bf(x1.y); o[6]=f2bf(x1.z); o[7]=f2bf(x1.w);
    *(ushort8*)(outp + idx) = o;
}

// ---------------------------------------------------------------------------
// Prep: seq [B][512][1024] f32 -> seqT [B][1024][512] bf16 (tiled transpose)
// ---------------------------------------------------------------------------
__global__ __launch_bounds__(256) void transpose_cvt_seq(const float* __restrict__ in,
                                                         unsigned short* __restrict__ outp)
{
    int b = blockIdx.z;
    int h0 = blockIdx.x*32, l0 = blockIdx.y*32;
    __shared__ float tile[32][33];
    int tx = threadIdx.x & 31, ty = threadIdx.x >> 5;
    #pragma unroll
    for (int p = 0; p < 4; ++p)
        tile[ty + p*8][tx] = in[((size_t)b*L_ + l0 + ty + p*8)*H_ + h0 + tx];
    __syncthreads();
    #pragma unroll
    for (int p = 0; p < 4; ++p)
        outp[((size_t)b*H_ + h0 + ty + p*8)*L_ + l0 + tx] = f2bf(tile[tx][ty + p*8]);
}

// ---------------------------------------------------------------------------
// Prep: W [2048][768] f32 -> WT_dup [768][4096] bf16 (K duplicated for hi|lo)
// z selects Wh->WhT or Wt->WtT
// ---------------------------------------------------------------------------
__global__ __launch_bounds__(256) void transpose_cvt_W(const float* __restrict__ Wh,
                                                       const float* __restrict__ Wt,
                                                       unsigned short* __restrict__ WhT,
                                                       unsigned short* __restrict__ WtT)
{
    const float* in = blockIdx.z ? Wt : Wh;
    unsigned short* outp = blockIdx.z ? WtT : WhT;
    int n0 = blockIdx.x*32, k0 = blockIdx.y*32;
    __shared__ float tile[32][33];
    int tx = threadIdx.x & 31, ty = threadIdx.x >> 5;
    #pragma unroll
    for (int p = 0; p < 4; ++p)
        tile[ty + p*8][tx] = in[((size_t)(k0 + ty + p*8))*D_ + n0 + tx];
    __syncthreads();
    #pragma unroll
    for (int p = 0; p < 4; ++p) {
        int n = n0 + ty + p*8;
        unsigned short v = f2bf(tile[tx][ty + p*8]);
        outp[(size_t)n*4096 + k0 + tx] = v;
        outp[(size_t)n*4096 + 2048 + k0 + tx] = v;
    }
}

// ---------------------------------------------------------------------------
// Prep: gathered hcat rows -> split-bf16 A matrices Ah/At [4096][4096]
// layout: [0,1024)=ent_hi [1024,2048)=rel_hi [2048,3072)=ent_lo [3072,4096)=rel_lo
// ---------------------------------------------------------------------------
__global__ __launch_bounds__(256) void prep_hcat(const float* __restrict__ ent_emb,
                                                 const float* __restrict__ rel,
                                                 const int* __restrict__ hts,
                                                 unsigned short* __restrict__ Ah,
                                                 unsigned short* __restrict__ At)
{
    int n = blockIdx.x, b = n >> 10;
    int hidx = hts[n*2], tidx = hts[n*2 + 1];
    const float* eh = ent_emb + (size_t)(b*E_ + hidx)*H_;
    const float* et = ent_emb + (size_t)(b*E_ + tidx)*H_;
    const float* rl = rel + (size_t)n*H_;
    int k8 = threadIdx.x * 8;
    #pragma unroll
    for (int m = 0; m < 2; ++m) {
        const float* esrc = m ? et : eh;
        unsigned short* dst = (m ? At : Ah) + (size_t)n*4096;
        const float* src = (k8 < 1024) ? (esrc + k8) : (rl + (k8 - 1024));
        float4 x0 = *(const float4*)src;
        float4 x1 = *(const float4*)(src + 4);
        float xs[8] = {x0.x,x0.y,x0.z,x0.w,x1.x,x1.y,x1.z,x1.w};
        ushort8 hi, lo;
        #pragma unroll
        for (int t = 0; t < 8; ++t) {
            unsigned short h = f2bf(xs[t]);
            hi[t] = h;
            lo[t] = f2bf(xs[t] - bf2f(h));
        }
        *(ushort8*)(dst + k8) = hi;
        *(ushort8*)(dst + 2048 + k8) = lo;
    }
}

// ---------------------------------------------------------------------------
// Prep: Wb [49152][97] f32 -> WbT [12][64][128][64] bf16 (c padded to 128, zeros)
// ---------------------------------------------------------------------------
__global__ __launch_bounds__(256) void prep_WbT(const float* __restrict__ Wb,
                                                unsigned short* __restrict__ outp)
{
    int blk = blockIdx.x;                 // kb*64 + i
    __shared__ float sW[64*97];
    const float* src = Wb + (size_t)blk*64*97;
    for (int e = threadIdx.x; e < 64*97; e += 256) sW[e] = src[e];
    __syncthreads();
    unsigned short* dst = outp + (size_t)blk*128*64;
    for (int e = threadIdx.x; e < 128*64; e += 256) {
        int c = e >> 6, j = e & 63;
        dst[e] = (c < C_) ? f2bf(sW[j*97 + c]) : (unsigned short)0;
    }
}

// ---------------------------------------------------------------------------
// Shared bf16 MFMA GEMM core: 128x128 tile, BK=32, 4 waves (2x2), each wave
// 64x64 as 4x4 tiles of 16x16x32. A [M][K] row-major bf16, Bt [N][K] bf16.
// ---------------------------------------------------------------------------
__device__ __forceinline__ void gemm128_core(const unsigned short* __restrict__ A,
                                             const unsigned short* __restrict__ Bt,
                                             int K, int row0, int col0,
                                             f4 (&acc)[4][4])
{
    __shared__ __attribute__((aligned(16))) unsigned short As[128][40]; // stride 40 bf16: 16B-aligned rows, 2-way-free banks
    __shared__ __attribute__((aligned(16))) unsigned short Bs[128][40];
    int tid = threadIdx.x;
    int wave = tid >> 6, lane = tid & 63;
    int wr = wave & 1, wc = wave >> 1;
    int lm = lane & 15, quad = lane >> 4;

    for (int k0 = 0; k0 < K; k0 += 32) {
        #pragma unroll
        for (int s = 0; s < 2; ++s) {
            int ch = tid + s*256;
            int row = ch >> 2, part = ch & 3;
            *(ushort8*)&As[row][part*8] = *(const ushort8*)(A + (size_t)(row0 + row)*K + k0 + part*8);
            *(ushort8*)&Bs[row][part*8] = *(const ushort8*)(Bt + (size_t)(col0 + row)*K + k0 + part*8);
        }
        __syncthreads();
        s8 a[4], b[4];
        #pragma unroll
        for (int ti = 0; ti < 4; ++ti) a[ti] = *(const s8*)&As[wr*64 + ti*16 + lm][quad*8];
        #pragma unroll
        for (int tj = 0; tj < 4; ++tj) b[tj] = *(const s8*)&Bs[wc*64 + tj*16 + lm][quad*8];
        #pragma unroll
        for (int ti = 0; ti < 4; ++ti)
            #pragma unroll
            for (int tj = 0; tj < 4; ++tj)
                acc[ti][tj] = __builtin_amdgcn_mfma_f32_16x16x32_bf16(a[ti], b[tj], acc[ti][tj], 0, 0, 0);
        __syncthreads();
    }
}

// ---------------------------------------------------------------------------
// Kernel 3: rel = ht_attn @ seq per batch, bf16 MFMA. grid (8,8,4)
// ---------------------------------------------------------------------------
__global__ __launch_bounds__(256) void gemm_rel_mfma(const unsigned short* __restrict__ htA,
                                                     const unsigned short* __restrict__ seqT,
                                                     float* __restrict__ rel)
{
    int z = blockIdx.z;
    const unsigned short* A  = htA  + (size_t)z*R_*L_;
    const unsigned short* Bt = seqT + (size_t)z*H_*L_;
    float* C = rel + (size_t)z*R_*H_;
    int row0 = blockIdx.y*128, col0 = blockIdx.x*128;
    f4 acc[4][4] = {};
    gemm128_core(A, Bt, L_, row0, col0, acc);
    int lane = threadIdx.x & 63, wave = threadIdx.x >> 6;
    int wr = wave & 1, wc = wave >> 1, lm = lane & 15, quad = lane >> 4;
    #pragma unroll
    for (int ti = 0; ti < 4; ++ti)
        #pragma unroll
        for (int tj = 0; tj < 4; ++tj)
            #pragma unroll
            for (int r = 0; r < 4; ++r) {
                int row = row0 + wr*64 + ti*16 + quad*4 + r;
                int col = col0 + wc*64 + tj*16 + lm;
                C[(size_t)row*H_ + col] = acc[ti][tj][r];
            }
}

// ---------------------------------------------------------------------------
// Kernel 4: extractor GEMM (split-bf16 K=4096) + bias + tanh. grid (6,32,2)
// ---------------------------------------------------------------------------
__global__ __launch_bounds__(256) void gemm_ext_mfma(
    const unsigned short* __restrict__ Ah, const unsigned short* __restrict__ At,
    const unsigned short* __restrict__ WhT, const unsigned short* __restrict__ WtT,
    const float* __restrict__ bh, const float* __restrict__ bt,
    float* __restrict__ hv, float* __restrict__ tv)
{
    int z = blockIdx.z;
    const unsigned short* A  = z ? At  : Ah;
    const unsigned short* Bt = z ? WtT : WhT;
    const float* bias = z ? bt : bh;
    float* C = z ? tv : hv;
    int row0 = blockIdx.y*128, col0 = blockIdx.x*128;
    f4 acc[4][4] = {};
    gemm128_core(A, Bt, 4096, row0, col0, acc);
    int lane = threadIdx.x & 63, wave = threadIdx.x >> 6;
    int wr = wave & 1, wc = wave >> 1, lm = lane & 15, quad = lane >> 4;
    #pragma unroll
    for (int ti = 0; ti < 4; ++ti)
        #pragma unroll
        for (int tj = 0; tj < 4; ++tj)
            #pragma unroll
            for (int r = 0; r < 4; ++r) {
                int row = row0 + wr*64 + ti*16 + quad*4 + r;
                int col = col0 + wc*64 + tj*16 + lm;
                float x = acc[ti][tj][r] + bias[col];
                float e = __expf(2.f*x);
                C[(size_t)row*D_ + col] = 1.f - 2.f/(e + 1.f);   // tanh
            }
}

// ---------------------------------------------------------------------------
// Kernel 5a: init output with bias
// ---------------------------------------------------------------------------
__global__ void out_init(const float* __restrict__ bb, float* __restrict__ out)
{
    int i = blockIdx.x*256 + threadIdx.x;
    if (i < NROW*C_) out[i] = bb[i % C_];
}

// ---------------------------------------------------------------------------
// Kernel 5b: block-bilinear classifier, MFMA, split-K over kb.
// Block: 64 rows x 128 cols (97 used), 4 waves (wr,wc), each wave 2 row-tiles
// x 4 col-tiles of 16x16x32. A-frag built in-register: hv[m,i]*tv[m,j].
// grid (64 rowtiles, 12 kb). Atomic f32 accumulation into bias-init out.
// ---------------------------------------------------------------------------
__global__ __launch_bounds__(256) void final_mfma(const float* __restrict__ hv,
                                                  const float* __restrict__ tv,
                                                  const unsigned short* __restrict__ WbT,
                                                  float* __restrict__ out)
{
    int row0 = blockIdx.x * 64;
    int kb   = blockIdx.y;
    __shared__ __attribute__((aligned(16))) float hvS[64][68];
    __shared__ __attribute__((aligned(16))) float tvS[64][68];
    __shared__ __attribute__((aligned(16))) unsigned short Ws[2][128*64]; // xor-swizzled granules

    int tid = threadIdx.x;
    // stage hv/tv kb-slices (64 rows x 64) as f32
    for (int e = tid; e < 1024; e += 256) {
        int r = e >> 4, part = e & 15;
        *(float4*)&hvS[r][part*4] = *(const float4*)(hv + (size_t)(row0 + r)*D_ + kb*BLK_ + part*4);
        *(float4*)&tvS[r][part*4] = *(const float4*)(tv + (size_t)(row0 + r)*D_ + kb*BLK_ + part*4);
    }
    int wave = tid >> 6, lane = tid & 63;
    int wr = wave & 1, wc = wave >> 1;
    int lm = lane & 15, quad = lane >> 4;
    __syncthreads();

    // preload tv fragments: constant across i within this kb
    float tvv[2][2][8];   // [rowtile][jhalf][t]
    #pragma unroll
    for (int rt = 0; rt < 2; ++rt)
        #pragma unroll
        for (int j2 = 0; j2 < 2; ++j2) {
            int r = wr*32 + rt*16 + lm;
            float4 p0 = *(const float4*)&tvS[r][j2*32 + quad*8];
            float4 p1 = *(const float4*)&tvS[r][j2*32 + quad*8 + 4];
            tvv[rt][j2][0]=p0.x; tvv[rt][j2][1]=p0.y; tvv[rt][j2][2]=p0.z; tvv[rt][j2][3]=p0.w;
            tvv[rt][j2][4]=p1.x; tvv[rt][j2][5]=p1.y; tvv[rt][j2][6]=p1.z; tvv[rt][j2][7]=p1.w;
        }

    f4 acc[2][4] = {};
    const unsigned short* wbase = WbT + (size_t)kb*64*128*64;

    for (int i0 = 0; i0 < 64; i0 += 2) {
        __syncthreads();
        // stage Wb slices for i0, i0+1 with xor swizzle on 8-bf16 granules
        for (int ch = tid; ch < 2048; ch += 256) {
            int ip = ch >> 10, rem = ch & 1023, c = rem >> 3, g = rem & 7;
            ushort8 v = *(const ushort8*)(wbase + (size_t)((i0 + ip)*128 + c)*64 + g*8);
            *(ushort8*)&Ws[ip][c*64 + ((g ^ (c & 7))*8)] = v;
        }
        __syncthreads();
        #pragma unroll
        for (int ip = 0; ip < 2; ++ip) {
            int i = i0 + ip;
            float sh0 = hvS[wr*32 + lm][i];
            float sh1 = hvS[wr*32 + 16 + lm][i];
            #pragma unroll
            for (int j2 = 0; j2 < 2; ++j2) {
                // build A-frags: bf16-truncate(sh * tvv) packed via v_perm
                s8 afr[2];
                #pragma unroll
                for (int rt = 0; rt < 2; ++rt) {
                    float sh = rt ? sh1 : sh0;
                    union { unsigned u[4]; s8 v; } cv;
                    #pragma unroll
                    for (int t2 = 0; t2 < 4; ++t2) {
                        float pe = sh * tvv[rt][j2][t2*2];
                        float po = sh * tvv[rt][j2][t2*2 + 1];
                        cv.u[t2] = __builtin_amdgcn_perm(__builtin_bit_cast(unsigned, po),
                                                         __builtin_bit_cast(unsigned, pe),
                                                         0x07060302u);
                    }
                    afr[rt] = cv.v;
                }
                #pragma unroll
                for (int ct = 0; ct < 4; ++ct) {
                    int c = wc*64 + ct*16 + lm;
                    int g = j2*4 + quad;
                    s8 bfr = *(const s8*)&Ws[ip][c*64 + ((g ^ (c & 7))*8)];
                    acc[0][ct] = __builtin_amdgcn_mfma_f32_16x16x32_bf16(afr[0], bfr, acc[0][ct], 0, 0, 0);
                    acc[1][ct] = __builtin_amdgcn_mfma_f32_16x16x32_bf16(afr[1], bfr, acc[1][ct], 0, 0, 0);
                }
            }
        }
    }

    #pragma unroll
    for (int rt = 0; rt < 2; ++rt)
        #pragma unroll
        for (int ct = 0; ct < 4; ++ct)
            #pragma unroll
            for (int r = 0; r < 4; ++r) {
                int row = row0 + wr*32 + rt*16 + quad*4 + r;
                int col = wc*64 + ct*16 + lm;
                if (col < C_) atomicAdd(out + (size_t)row*C_ + col, acc[rt][ct][r]);
            }
}

// ---------------------------------------------------------------------------
extern "C" void kernel_launch(void* const* d_in, const int* in_sizes, int n_in,
                              void* d_out, int out_size, void* d_ws, size_t ws_size,
                              hipStream_t stream)
{
    const float* seq_lhs = (const float*)d_in[0];
    const float* ent_lhs = (const float*)d_in[1];
    const float* attn    = (const float*)d_in[2];
    const int*   labels  = (const int*)d_in[3];
    const int*   hts     = (const int*)d_in[4];
    const float* Wh      = (const float*)d_in[5];
    const float* bh      = (const float*)d_in[6];
    const float* Wt      = (const float*)d_in[7];
    const float* bt      = (const float*)d_in[8];
    const float* Wb      = (const float*)d_in[9];
    const float* bb      = (const float*)d_in[10];
    float* out = (float*)d_out;

    float* ws       = (float*)d_ws;
    float* ent_emb  = ws;                       // 262144 f32
    float* ent_attn = ent_emb  + 262144;        // 2097152
    float* ht_attn  = ent_attn + 2097152;       // 2097152
    float* rel      = ht_attn  + 2097152;       // 4194304
    float* hv       = rel      + 4194304;       // 3145728
    float* tv       = hv       + 3145728;       // 3145728
    unsigned short* htA  = (unsigned short*)(tv + 3145728); // 2097152 bf16
    unsigned short* seqT = htA  + 2097152;      // 2097152
    unsigned short* WhT  = seqT + 2097152;      // 3145728
    unsigned short* WtT  = WhT  + 3145728;      // 3145728
    unsigned short* Ah   = WtT  + 3145728;      // 16777216
    unsigned short* At   = Ah   + 16777216;     // 16777216
    unsigned short* WbT  = At   + 16777216;     // 6291456
    // total ~160.4 MB

    // independent weight preps first
    transpose_cvt_W<<<dim3(24, 64, 2), 256, 0, stream>>>(Wh, Wt, WhT, WtT);
    prep_WbT<<<KB_*64, 256, 0, stream>>>(Wb, WbT);
    transpose_cvt_seq<<<dim3(32, 16, B_), 256, 0, stream>>>(seq_lhs, seqT);

    pool_kernel<<<B_*E_, 256, 0, stream>>>(ent_lhs, attn, labels, ent_emb, ent_attn);
    pair_attn_kernel<<<B_*R_, 256, 0, stream>>>(ent_attn, hts, ht_attn);
    cvt_ht<<<1024, 256, 0, stream>>>(ht_attn, htA);
    gemm_rel_mfma<<<dim3(8, 8, B_), 256, 0, stream>>>(htA, seqT, rel);
    prep_hcat<<<NROW, 256, 0, stream>>>(ent_emb, rel, hts, Ah, At);
    gemm_ext_mfma<<<dim3(6, 32, 2), 256, 0, stream>>>(Ah, At, WhT, WtT, bh, bt, hv, tv);
    out_init<<<(NROW*C_ + 255)/256, 256, 0, stream>>>(bb, out);
    final_mfma<<<dim3(NROW/64, KB_), 256, 0, stream>>>(hv, tv, WbT, out);
}

// Round 6
// 512.446 us; speedup vs baseline: 4.5084x; 1.1289x over previous
//
#include <hip/hip_runtime.h>
#include <hip/hip_bf16.h>
#include <math.h>

// Problem constants
#define B_  4
#define L_  512
#define H_  1024
#define M_  128
#define E_  64
#define NH_ 16
#define R_  1024
#define D_  768
#define BLK_ 64
#define C_  97
#define NROW (B_*R_)          // 4096
#define KB_  (D_/BLK_)        // 12

typedef __attribute__((ext_vector_type(8))) unsigned short ushort8;
typedef __attribute__((ext_vector_type(8))) short s8;       // 8 bf16 MFMA operand
typedef __attribute__((ext_vector_type(4))) float f4;       // MFMA C/D

__device__ __forceinline__ unsigned short f2bf(float x) {   // RNE f32->bf16
    unsigned u = __builtin_bit_cast(unsigned, x);
    unsigned r = (u + 0x7fffu + ((u >> 16) & 1u)) >> 16;
    return (unsigned short)r;
}
__device__ __forceinline__ float bf2f(unsigned short h) {
    unsigned u = ((unsigned)h) << 16;
    return __builtin_bit_cast(float, u);
}

// ===========================================================================
// Stage 1: entity pooling (R2-verified source, f32 outputs)
// ===========================================================================
__global__ __launch_bounds__(256) void pool_kernel(
    const float* __restrict__ ent_lhs, const float* __restrict__ attn,
    const int* __restrict__ labels,
    float* __restrict__ ent_emb, float* __restrict__ ent_attn)
{
    int be = blockIdx.x, b = be >> 6, e = be & 63;
    __shared__ int midx[M_];
    __shared__ int scnt;
    if (threadIdx.x == 0) scnt = 0;
    __syncthreads();
    if (threadIdx.x < M_) {
        if (labels[b*M_ + threadIdx.x] == e) {
            int p = atomicAdd(&scnt, 1);
            midx[p] = threadIdx.x;
        }
    }
    __syncthreads();
    int cnt = scnt;
    for (int h = threadIdx.x; h < H_; h += blockDim.x) {
        float r = 0.f;
        if (cnt > 0) {
            const float* base = ent_lhs + (size_t)b*M_*H_ + h;
            float mx = -INFINITY;
            for (int k = 0; k < cnt; ++k) mx = fmaxf(mx, base[(size_t)midx[k]*H_]);
            float s = 0.f;
            for (int k = 0; k < cnt; ++k) s += expf(base[(size_t)midx[k]*H_] - mx);
            r = mx + logf(s);
        }
        ent_emb[(size_t)be*H_ + h] = r;
    }
    float inv = (cnt > 0) ? 1.f/(float)cnt : 0.f;
    for (int x = threadIdx.x; x < NH_*L_; x += blockDim.x) {
        int nh = x >> 9, l = x & (L_-1);
        const float* base = attn + (((size_t)b*NH_ + nh)*M_)*L_ + l;
        float s = 0.f;
        for (int k = 0; k < cnt; ++k) s += base[(size_t)midx[k]*L_];
        ent_attn[((size_t)be*NH_ + nh)*L_ + l] = s * inv;
    }
}

// ===========================================================================
// Stage 2: pair attention (R2-verified source, f32)
// ===========================================================================
__global__ __launch_bounds__(256) void pair_attn_kernel(
    const float* __restrict__ ent_attn, const int* __restrict__ hts,
    float* __restrict__ ht_attn)
{
    int br = blockIdx.x, b = br >> 10;
    int hi = hts[br*2 + 0], ti = hts[br*2 + 1];
    const float* ph = ent_attn + ((size_t)(b*E_ + hi)*NH_)*L_;
    const float* pt = ent_attn + ((size_t)(b*E_ + ti)*NH_)*L_;
    float v[2], part = 0.f;
    #pragma unroll
    for (int q = 0; q < 2; ++q) {
        int l = threadIdx.x + q*256;
        float s = 0.f;
        #pragma unroll
        for (int nh = 0; nh < NH_; ++nh) s += ph[nh*L_ + l] * pt[nh*L_ + l];
        v[q] = s * (1.f/(float)NH_);
        part += v[q];
    }
    __shared__ float red[4];
    #pragma unroll
    for (int off = 32; off > 0; off >>= 1) part += __shfl_down(part, off, 64);
    if ((threadIdx.x & 63) == 0) red[threadIdx.x >> 6] = part;
    __syncthreads();
    float norm = 1.f / (red[0] + red[1] + red[2] + red[3] + 1e-5f);
    #pragma unroll
    for (int q = 0; q < 2; ++q)
        ht_attn[(size_t)br*L_ + threadIdx.x + q*256] = v[q] * norm;
}

// ===========================================================================
// Conversions / layout preps
// ===========================================================================
__global__ __launch_bounds__(256) void cvt_ht(const float* __restrict__ in,
                                              unsigned short* __restrict__ outp)
{
    size_t idx = ((size_t)blockIdx.x*256 + threadIdx.x)*8;
    float4 x0 = *(const float4*)(in + idx);
    float4 x1 = *(const float4*)(in + idx + 4);
    ushort8 o;
    o[0]=f2bf(x0.x); o[1]=f2bf(x0.y); o[2]=f2bf(x0.z); o[3]=f2bf(x0.w);
    o[4]=f2bf(x1.x); o[5]=f2bf(x1.y); o[6]=f2bf(x1.z); o[7]=f2bf(x1.w);
    *(ushort8*)(outp + idx) = o;
}

// seq [B][512][1024] f32 -> seqT [B][1024][512] bf16 (tiled transpose)
__global__ __launch_bounds__(256) void transpose_cvt_seq(const float* __restrict__ in,
                                                         unsigned short* __restrict__ outp)
{
    int b = blockIdx.z;
    int h0 = blockIdx.x*32, l0 = blockIdx.y*32;
    __shared__ float tile[32][33];
    int tx = threadIdx.x & 31, ty = threadIdx.x >> 5;
    #pragma unroll
    for (int p = 0; p < 4; ++p)
        tile[ty + p*8][tx] = in[((size_t)b*L_ + l0 + ty + p*8)*H_ + h0 + tx];
    __syncthreads();
    #pragma unroll
    for (int p = 0; p < 4; ++p)
        outp[((size_t)b*H_ + h0 + ty + p*8)*L_ + l0 + tx] = f2bf(tile[tx][ty + p*8]);
}

// W [2048][768] f32 -> WT [768][2048] bf16 (single-precision-bf16, no K dup)
__global__ __launch_bounds__(256) void transpose_cvt_W(const float* __restrict__ Wh,
                                                       const float* __restrict__ Wt,
                                                       unsigned short* __restrict__ WhT,
                                                       unsigned short* __restrict__ WtT)
{
    const float* in = blockIdx.z ? Wt : Wh;
    unsigned short* outp = blockIdx.z ? WtT : WhT;
    int n0 = blockIdx.x*32, k0 = blockIdx.y*32;
    __shared__ float tile[32][33];
    int tx = threadIdx.x & 31, ty = threadIdx.x >> 5;
    #pragma unroll
    for (int p = 0; p < 4; ++p)
        tile[ty + p*8][tx] = in[((size_t)(k0 + ty + p*8))*D_ + n0 + tx];
    __syncthreads();
    #pragma unroll
    for (int p = 0; p < 4; ++p) {
        int n = n0 + ty + p*8;
        outp[(size_t)n*2048 + k0 + tx] = f2bf(tile[tx][ty + p*8]);
    }
}

// gathered hcat rows -> single-bf16 A matrices Ah/At [4096][2048]
// cols [0,1024) = gathered ent_emb row; [1024,2048) = rel row
__global__ __launch_bounds__(256) void prep_hcat(const float* __restrict__ ent_emb,
                                                 const float* __restrict__ rel,
                                                 const int* __restrict__ hts,
                                                 unsigned short* __restrict__ Ah,
                                                 unsigned short* __restrict__ At)
{
    int n = blockIdx.x, b = n >> 10;
    int hidx = hts[n*2], tidx = hts[n*2 + 1];
    const float* eh = ent_emb + (size_t)(b*E_ + hidx)*H_;
    const float* et = ent_emb + (size_t)(b*E_ + tidx)*H_;
    const float* rl = rel + (size_t)n*H_;
    int k8 = threadIdx.x * 8;     // 0..2040
    #pragma unroll
    for (int m = 0; m < 2; ++m) {
        const float* esrc = m ? et : eh;
        unsigned short* dst = (m ? At : Ah) + (size_t)n*2048;
        const float* src = (k8 < 1024) ? (esrc + k8) : (rl + (k8 - 1024));
        float4 x0 = *(const float4*)src;
        float4 x1 = *(const float4*)(src + 4);
        ushort8 o;
        o[0]=f2bf(x0.x); o[1]=f2bf(x0.y); o[2]=f2bf(x0.z); o[3]=f2bf(x0.w);
        o[4]=f2bf(x1.x); o[5]=f2bf(x1.y); o[6]=f2bf(x1.z); o[7]=f2bf(x1.w);
        *(ushort8*)(dst + k8) = o;
    }
}

// Wb [49152][97] f32 -> WbT [12][64][128][64] bf16 (c padded to 128, zeros)
__global__ __launch_bounds__(256) void prep_WbT(const float* __restrict__ Wb,
                                                unsigned short* __restrict__ outp)
{
    int blk = blockIdx.x;                 // kb*64 + i
    __shared__ float sW[64*97];
    const float* src = Wb + (size_t)blk*64*97;
    for (int e = threadIdx.x; e < 64*97; e += 256) sW[e] = src[e];
    __syncthreads();
    unsigned short* dst = outp + (size_t)blk*128*64;
    for (int e = threadIdx.x; e < 128*64; e += 256) {
        int c = e >> 6, j = e & 63;
        dst[e] = (c < C_) ? f2bf(sW[j*97 + c]) : (unsigned short)0;
    }
}

// ===========================================================================
// bf16 MFMA GEMM core (R2-verified): 128x128 tile, BK=32, 2x2 waves
// ===========================================================================
__device__ __forceinline__ void gemm128_core(const unsigned short* __restrict__ A,
                                             const unsigned short* __restrict__ Bt,
                                             int K, int row0, int col0,
                                             f4 (&acc)[4][4])
{
    __shared__ __attribute__((aligned(16))) unsigned short As[128][40];
    __shared__ __attribute__((aligned(16))) unsigned short Bs[128][40];
    int tid = threadIdx.x;
    int wave = tid >> 6, lane = tid & 63;
    int wr = wave & 1, wc = wave >> 1;
    int lm = lane & 15, quad = lane >> 4;

    for (int k0 = 0; k0 < K; k0 += 32) {
        #pragma unroll
        for (int s = 0; s < 2; ++s) {
            int ch = tid + s*256;
            int row = ch >> 2, part = ch & 3;
            *(ushort8*)&As[row][part*8] = *(const ushort8*)(A + (size_t)(row0 + row)*K + k0 + part*8);
            *(ushort8*)&Bs[row][part*8] = *(const ushort8*)(Bt + (size_t)(col0 + row)*K + k0 + part*8);
        }
        __syncthreads();
        s8 a[4], b[4];
        #pragma unroll
        for (int ti = 0; ti < 4; ++ti) a[ti] = *(const s8*)&As[wr*64 + ti*16 + lm][quad*8];
        #pragma unroll
        for (int tj = 0; tj < 4; ++tj) b[tj] = *(const s8*)&Bs[wc*64 + tj*16 + lm][quad*8];
        #pragma unroll
        for (int ti = 0; ti < 4; ++ti)
            #pragma unroll
            for (int tj = 0; tj < 4; ++tj)
                acc[ti][tj] = __builtin_amdgcn_mfma_f32_16x16x32_bf16(a[ti], b[tj], acc[ti][tj], 0, 0, 0);
        __syncthreads();
    }
}

// ===========================================================================
// Stage 3: rel = ht_attn @ seq per batch -> f32 rel (R2-verified)
// ===========================================================================
__global__ __launch_bounds__(256) void gemm_rel_mfma(const unsigned short* __restrict__ htA,
                                                     const unsigned short* __restrict__ seqT,
                                                     float* __restrict__ rel)
{
    int z = blockIdx.z;
    const unsigned short* A  = htA  + (size_t)z*R_*L_;
    const unsigned short* Bt = seqT + (size_t)z*H_*L_;
    float* C = rel + (size_t)z*R_*H_;
    int row0 = blockIdx.y*128, col0 = blockIdx.x*128;
    f4 acc[4][4] = {};
    gemm128_core(A, Bt, L_, row0, col0, acc);
    int lane = threadIdx.x & 63, wave = threadIdx.x >> 6;
    int wr = wave & 1, wc = wave >> 1, lm = lane & 15, quad = lane >> 4;
    #pragma unroll
    for (int ti = 0; ti < 4; ++ti)
        #pragma unroll
        for (int tj = 0; tj < 4; ++tj)
            #pragma unroll
            for (int r = 0; r < 4; ++r) {
                int row = row0 + wr*64 + ti*16 + quad*4 + r;
                int col = col0 + wc*64 + tj*16 + lm;
                C[(size_t)row*H_ + col] = acc[ti][tj][r];
            }
}

// ===========================================================================
// Stage 4: extractor GEMM (single-bf16, K=2048) + bias + tanh -> f32 hv/tv
// ===========================================================================
__global__ __launch_bounds__(256) void gemm_ext_mfma(
    const unsigned short* __restrict__ Ah, const unsigned short* __restrict__ At,
    const unsigned short* __restrict__ WhT, const unsigned short* __restrict__ WtT,
    const float* __restrict__ bh, const float* __restrict__ bt,
    float* __restrict__ hv, float* __restrict__ tv)
{
    int z = blockIdx.z;
    const unsigned short* A  = z ? At  : Ah;
    const unsigned short* Bt = z ? WtT : WhT;
    const float* bias = z ? bt : bh;
    float* C = z ? tv : hv;
    int row0 = blockIdx.y*128, col0 = blockIdx.x*128;
    f4 acc[4][4] = {};
    gemm128_core(A, Bt, 2048, row0, col0, acc);
    int lane = threadIdx.x & 63, wave = threadIdx.x >> 6;
    int wr = wave & 1, wc = wave >> 1, lm = lane & 15, quad = lane >> 4;
    #pragma unroll
    for (int ti = 0; ti < 4; ++ti)
        #pragma unroll
        for (int tj = 0; tj < 4; ++tj)
            #pragma unroll
            for (int r = 0; r < 4; ++r) {
                int row = row0 + wr*64 + ti*16 + quad*4 + r;
                int col = col0 + wc*64 + tj*16 + lm;
                float x = acc[ti][tj][r] + bias[col];
                float e = __expf(2.f*x);
                C[(size_t)row*D_ + col] = 1.f - 2.f/(e + 1.f);   // tanh
            }
}

// ===========================================================================
// Stage 5a: init output with bias
// ===========================================================================
__global__ void out_init(const float* __restrict__ bb, float* __restrict__ out)
{
    int i = blockIdx.x*256 + threadIdx.x;
    if (i < NROW*C_) out[i] = bb[i % C_];
}

// ===========================================================================
// Stage 5b: block-bilinear classifier — VERBATIM copy of the R2-passing
// final_mfma (f32 LDS for hv/tv, scalar pe/po products). Do not modify.
// 64 rows x 128 cols per block, 2x2 waves, wave = 32rows(2rt) x 64cols(4ct).
// grid (64 rowtiles, 12 kb), f32 atomics into bias-initialized out.
// ===========================================================================
__global__ __launch_bounds__(256) void final_mfma(
    const float* __restrict__ hv,             // [4096][768] f32
    const float* __restrict__ tv,
    const unsigned short* __restrict__ WbT,   // [12][64][128][64] bf16
    float* __restrict__ out)                  // [4096][97] f32
{
    int row0 = blockIdx.x * 64;
    int kb   = blockIdx.y;
    __shared__ __attribute__((aligned(16))) float hvS[64][68];
    __shared__ __attribute__((aligned(16))) float tvS[64][68];
    __shared__ __attribute__((aligned(16))) unsigned short Ws[2][128*64];

    int tid = threadIdx.x;
    // stage hv/tv kb-slices (64 rows x 64) as f32
    for (int e = tid; e < 1024; e += 256) {
        int r = e >> 4, part = e & 15;
        *(float4*)&hvS[r][part*4] = *(const float4*)(hv + (size_t)(row0 + r)*D_ + kb*BLK_ + part*4);
        *(float4*)&tvS[r][part*4] = *(const float4*)(tv + (size_t)(row0 + r)*D_ + kb*BLK_ + part*4);
    }
    int wave = tid >> 6, lane = tid & 63;
    int wr = wave & 1, wc = wave >> 1;
    int lm = lane & 15, quad = lane >> 4;
    __syncthreads();

    // preload tv fragments: constant across i within this kb
    float tvv[2][2][8];   // [rowtile][jhalf][t]
    #pragma unroll
    for (int rt = 0; rt < 2; ++rt)
        #pragma unroll
        for (int j2 = 0; j2 < 2; ++j2) {
            int r = wr*32 + rt*16 + lm;
            float4 p0 = *(const float4*)&tvS[r][j2*32 + quad*8];
            float4 p1 = *(const float4*)&tvS[r][j2*32 + quad*8 + 4];
            tvv[rt][j2][0]=p0.x; tvv[rt][j2][1]=p0.y; tvv[rt][j2][2]=p0.z; tvv[rt][j2][3]=p0.w;
            tvv[rt][j2][4]=p1.x; tvv[rt][j2][5]=p1.y; tvv[rt][j2][6]=p1.z; tvv[rt][j2][7]=p1.w;
        }

    f4 acc[2][4] = {};
    const unsigned short* wbase = WbT + (size_t)kb*64*128*64;

    for (int i0 = 0; i0 < 64; i0 += 2) {
        __syncthreads();
        // stage Wb slices for i0, i0+1 with xor swizzle on 8-bf16 granules
        for (int ch = tid; ch < 2048; ch += 256) {
            int ip = ch >> 10, rem = ch & 1023, c = rem >> 3, g = rem & 7;
            ushort8 v = *(const ushort8*)(wbase + (size_t)((i0 + ip)*128 + c)*64 + g*8);
            *(ushort8*)&Ws[ip][c*64 + ((g ^ (c & 7))*8)] = v;
        }
        __syncthreads();
        #pragma unroll
        for (int ip = 0; ip < 2; ++ip) {
            int i = i0 + ip;
            float sh0 = hvS[wr*32 + lm][i];
            float sh1 = hvS[wr*32 + 16 + lm][i];
            #pragma unroll
            for (int j2 = 0; j2 < 2; ++j2) {
                // build A-frags: bf16-truncate(sh * tvv) packed via v_perm
                s8 afr[2];
                #pragma unroll
                for (int rt = 0; rt < 2; ++rt) {
                    float sh = rt ? sh1 : sh0;
                    union { unsigned u[4]; s8 v; } cv;
                    #pragma unroll
                    for (int t2 = 0; t2 < 4; ++t2) {
                        float pe = sh * tvv[rt][j2][t2*2];
                        float po = sh * tvv[rt][j2][t2*2 + 1];
                        cv.u[t2] = __builtin_amdgcn_perm(__builtin_bit_cast(unsigned, po),
                                                         __builtin_bit_cast(unsigned, pe),
                                                         0x07060302u);
                    }
                    afr[rt] = cv.v;
                }
                #pragma unroll
                for (int ct = 0; ct < 4; ++ct) {
                    int c = wc*64 + ct*16 + lm;
                    int g = j2*4 + quad;
                    s8 bfr = *(const s8*)&Ws[ip][c*64 + ((g ^ (c & 7))*8)];
                    acc[0][ct] = __builtin_amdgcn_mfma_f32_16x16x32_bf16(afr[0], bfr, acc[0][ct], 0, 0, 0);
                    acc[1][ct] = __builtin_amdgcn_mfma_f32_16x16x32_bf16(afr[1], bfr, acc[1][ct], 0, 0, 0);
                }
            }
        }
    }

    #pragma unroll
    for (int rt = 0; rt < 2; ++rt)
        #pragma unroll
        for (int ct = 0; ct < 4; ++ct)
            #pragma unroll
            for (int r = 0; r < 4; ++r) {
                int row = row0 + wr*32 + rt*16 + quad*4 + r;
                int col = wc*64 + ct*16 + lm;
                if (col < C_) atomicAdd(out + (size_t)row*C_ + col, acc[rt][ct][r]);
            }
}

// ===========================================================================
extern "C" void kernel_launch(void* const* d_in, const int* in_sizes, int n_in,
                              void* d_out, int out_size, void* d_ws, size_t ws_size,
                              hipStream_t stream)
{
    const float* seq_lhs = (const float*)d_in[0];
    const float* ent_lhs = (const float*)d_in[1];
    const float* attn    = (const float*)d_in[2];
    const int*   labels  = (const int*)d_in[3];
    const int*   hts     = (const int*)d_in[4];
    const float* Wh      = (const float*)d_in[5];
    const float* bh      = (const float*)d_in[6];
    const float* Wt      = (const float*)d_in[7];
    const float* bt      = (const float*)d_in[8];
    const float* Wb      = (const float*)d_in[9];
    const float* bb      = (const float*)d_in[10];
    float* out = (float*)d_out;

    float* ws       = (float*)d_ws;
    float* ent_emb  = ws;                       // 262144 f32
    float* ent_attn = ent_emb  + 262144;        // 2097152
    float* ht_attn  = ent_attn + 2097152;       // 2097152
    float* rel      = ht_attn  + 2097152;       // 4194304
    float* hv       = rel      + 4194304;       // 3145728
    float* tv       = hv       + 3145728;       // 3145728
    unsigned short* htA  = (unsigned short*)(tv + 3145728); // 2097152 bf16
    unsigned short* seqT = htA  + 2097152;      // 2097152
    unsigned short* WhT  = seqT + 2097152;      // 1572864  (K=2048, no dup)
    unsigned short* WtT  = WhT  + 1572864;      // 1572864
    unsigned short* Ah   = WtT  + 1572864;      // 8388608  ([4096][2048])
    unsigned short* At   = Ah   + 8388608;      // 8388608
    unsigned short* WbT  = At   + 8388608;      // 6291456
    // total ~120.6 MB

    // weight preps (independent of activations)
    transpose_cvt_W<<<dim3(24, 64, 2), 256, 0, stream>>>(Wh, Wt, WhT, WtT);
    prep_WbT<<<KB_*64, 256, 0, stream>>>(Wb, WbT);
    transpose_cvt_seq<<<dim3(32, 16, B_), 256, 0, stream>>>(seq_lhs, seqT);

    pool_kernel<<<B_*E_, 256, 0, stream>>>(ent_lhs, attn, labels, ent_emb, ent_attn);
    pair_attn_kernel<<<B_*R_, 256, 0, stream>>>(ent_attn, hts, ht_attn);
    cvt_ht<<<1024, 256, 0, stream>>>(ht_attn, htA);
    gemm_rel_mfma<<<dim3(8, 8, B_), 256, 0, stream>>>(htA, seqT, rel);
    prep_hcat<<<NROW, 256, 0, stream>>>(ent_emb, rel, hts, Ah, At);
    gemm_ext_mfma<<<dim3(6, 32, 2), 256, 0, stream>>>(Ah, At, WhT, WtT, bh, bt, hv, tv);
    out_init<<<(NROW*C_ + 255)/256, 256, 0, stream>>>(bb, out);
    final_mfma<<<dim3(NROW/64, KB_), 256, 0, stream>>>(hv, tv, WbT, out);
}

// Round 7
// 411.267 us; speedup vs baseline: 5.6176x; 1.2460x over previous
//
#include <hip/hip_runtime.h>
#include <hip/hip_bf16.h>
#include <math.h>

// Problem constants
#define B_  4
#define L_  512
#define H_  1024
#define M_  128
#define E_  64
#define NH_ 16
#define R_  1024
#define D_  768
#define BLK_ 64
#define C_  97
#define NROW (B_*R_)          // 4096
#define KB_  (D_/BLK_)        // 12

typedef __attribute__((ext_vector_type(8))) unsigned short ushort8;
typedef __attribute__((ext_vector_type(8))) short s8;       // 8 bf16 MFMA operand
typedef __attribute__((ext_vector_type(4))) float f4;       // MFMA C/D

__device__ __forceinline__ unsigned short f2bf(float x) {   // RNE f32->bf16
    unsigned u = __builtin_bit_cast(unsigned, x);
    unsigned r = (u + 0x7fffu + ((u >> 16) & 1u)) >> 16;
    return (unsigned short)r;
}
__device__ __forceinline__ float bf2f(unsigned short h) {
    unsigned u = ((unsigned)h) << 16;
    return __builtin_bit_cast(float, u);
}

// ===========================================================================
// Stage 1: entity pooling (R6-verified)
// ===========================================================================
__global__ __launch_bounds__(256) void pool_kernel(
    const float* __restrict__ ent_lhs, const float* __restrict__ attn,
    const int* __restrict__ labels,
    float* __restrict__ ent_emb, float* __restrict__ ent_attn)
{
    int be = blockIdx.x, b = be >> 6, e = be & 63;
    __shared__ int midx[M_];
    __shared__ int scnt;
    if (threadIdx.x == 0) scnt = 0;
    __syncthreads();
    if (threadIdx.x < M_) {
        if (labels[b*M_ + threadIdx.x] == e) {
            int p = atomicAdd(&scnt, 1);
            midx[p] = threadIdx.x;
        }
    }
    __syncthreads();
    int cnt = scnt;
    for (int h = threadIdx.x; h < H_; h += blockDim.x) {
        float r = 0.f;
        if (cnt > 0) {
            const float* base = ent_lhs + (size_t)b*M_*H_ + h;
            float mx = -INFINITY;
            for (int k = 0; k < cnt; ++k) mx = fmaxf(mx, base[(size_t)midx[k]*H_]);
            float s = 0.f;
            for (int k = 0; k < cnt; ++k) s += expf(base[(size_t)midx[k]*H_] - mx);
            r = mx + logf(s);
        }
        ent_emb[(size_t)be*H_ + h] = r;
    }
    float inv = (cnt > 0) ? 1.f/(float)cnt : 0.f;
    for (int x = threadIdx.x; x < NH_*L_; x += blockDim.x) {
        int nh = x >> 9, l = x & (L_-1);
        const float* base = attn + (((size_t)b*NH_ + nh)*M_)*L_ + l;
        float s = 0.f;
        for (int k = 0; k < cnt; ++k) s += base[(size_t)midx[k]*L_];
        ent_attn[((size_t)be*NH_ + nh)*L_ + l] = s * inv;
    }
}

// ===========================================================================
// Stage 2: pair attention (R6-verified)
// ===========================================================================
__global__ __launch_bounds__(256) void pair_attn_kernel(
    const float* __restrict__ ent_attn, const int* __restrict__ hts,
    float* __restrict__ ht_attn)
{
    int br = blockIdx.x, b = br >> 10;
    int hi = hts[br*2 + 0], ti = hts[br*2 + 1];
    const float* ph = ent_attn + ((size_t)(b*E_ + hi)*NH_)*L_;
    const float* pt = ent_attn + ((size_t)(b*E_ + ti)*NH_)*L_;
    float v[2], part = 0.f;
    #pragma unroll
    for (int q = 0; q < 2; ++q) {
        int l = threadIdx.x + q*256;
        float s = 0.f;
        #pragma unroll
        for (int nh = 0; nh < NH_; ++nh) s += ph[nh*L_ + l] * pt[nh*L_ + l];
        v[q] = s * (1.f/(float)NH_);
        part += v[q];
    }
    __shared__ float red[4];
    #pragma unroll
    for (int off = 32; off > 0; off >>= 1) part += __shfl_down(part, off, 64);
    if ((threadIdx.x & 63) == 0) red[threadIdx.x >> 6] = part;
    __syncthreads();
    float norm = 1.f / (red[0] + red[1] + red[2] + red[3] + 1e-5f);
    #pragma unroll
    for (int q = 0; q < 2; ++q)
        ht_attn[(size_t)br*L_ + threadIdx.x + q*256] = v[q] * norm;
}

// ===========================================================================
// Conversions / layout preps (all R6-verified)
// ===========================================================================
__global__ __launch_bounds__(256) void cvt_ht(const float* __restrict__ in,
                                              unsigned short* __restrict__ outp)
{
    size_t idx = ((size_t)blockIdx.x*256 + threadIdx.x)*8;
    float4 x0 = *(const float4*)(in + idx);
    float4 x1 = *(const float4*)(in + idx + 4);
    ushort8 o;
    o[0]=f2bf(x0.x); o[1]=f2bf(x0.y); o[2]=f2bf(x0.z); o[3]=f2bf(x0.w);
    o[4]=f2bf(x1.x); o[5]=f2bf(x1.y); o[6]=f2bf(x1.z); o[7]=f2bf(x1.w);
    *(ushort8*)(outp + idx) = o;
}

__global__ __launch_bounds__(256) void transpose_cvt_seq(const float* __restrict__ in,
                                                         unsigned short* __restrict__ outp)
{
    int b = blockIdx.z;
    int h0 = blockIdx.x*32, l0 = blockIdx.y*32;
    __shared__ float tile[32][33];
    int tx = threadIdx.x & 31, ty = threadIdx.x >> 5;
    #pragma unroll
    for (int p = 0; p < 4; ++p)
        tile[ty + p*8][tx] = in[((size_t)b*L_ + l0 + ty + p*8)*H_ + h0 + tx];
    __syncthreads();
    #pragma unroll
    for (int p = 0; p < 4; ++p)
        outp[((size_t)b*H_ + h0 + ty + p*8)*L_ + l0 + tx] = f2bf(tile[tx][ty + p*8]);
}

__global__ __launch_bounds__(256) void transpose_cvt_W(const float* __restrict__ Wh,
                                                       const float* __restrict__ Wt,
                                                       unsigned short* __restrict__ WhT,
                                                       unsigned short* __restrict__ WtT)
{
    const float* in = blockIdx.z ? Wt : Wh;
    unsigned short* outp = blockIdx.z ? WtT : WhT;
    int n0 = blockIdx.x*32, k0 = blockIdx.y*32;
    __shared__ float tile[32][33];
    int tx = threadIdx.x & 31, ty = threadIdx.x >> 5;
    #pragma unroll
    for (int p = 0; p < 4; ++p)
        tile[ty + p*8][tx] = in[((size_t)(k0 + ty + p*8))*D_ + n0 + tx];
    __syncthreads();
    #pragma unroll
    for (int p = 0; p < 4; ++p) {
        int n = n0 + ty + p*8;
        outp[(size_t)n*2048 + k0 + tx] = f2bf(tile[tx][ty + p*8]);
    }
}

__global__ __launch_bounds__(256) void prep_hcat(const float* __restrict__ ent_emb,
                                                 const float* __restrict__ rel,
                                                 const int* __restrict__ hts,
                                                 unsigned short* __restrict__ Ah,
                                                 unsigned short* __restrict__ At)
{
    int n = blockIdx.x, b = n >> 10;
    int hidx = hts[n*2], tidx = hts[n*2 + 1];
    const float* eh = ent_emb + (size_t)(b*E_ + hidx)*H_;
    const float* et = ent_emb + (size_t)(b*E_ + tidx)*H_;
    const float* rl = rel + (size_t)n*H_;
    int k8 = threadIdx.x * 8;     // 0..2040
    #pragma unroll
    for (int m = 0; m < 2; ++m) {
        const float* esrc = m ? et : eh;
        unsigned short* dst = (m ? At : Ah) + (size_t)n*2048;
        const float* src = (k8 < 1024) ? (esrc + k8) : (rl + (k8 - 1024));
        float4 x0 = *(const float4*)src;
        float4 x1 = *(const float4*)(src + 4);
        ushort8 o;
        o[0]=f2bf(x0.x); o[1]=f2bf(x0.y); o[2]=f2bf(x0.z); o[3]=f2bf(x0.w);
        o[4]=f2bf(x1.x); o[5]=f2bf(x1.y); o[6]=f2bf(x1.z); o[7]=f2bf(x1.w);
        *(ushort8*)(dst + k8) = o;
    }
}

__global__ __launch_bounds__(256) void prep_WbT(const float* __restrict__ Wb,
                                                unsigned short* __restrict__ outp)
{
    int blk = blockIdx.x;                 // kb*64 + i
    __shared__ float sW[64*97];
    const float* src = Wb + (size_t)blk*64*97;
    for (int e = threadIdx.x; e < 64*97; e += 256) sW[e] = src[e];
    __syncthreads();
    unsigned short* dst = outp + (size_t)blk*128*64;
    for (int e = threadIdx.x; e < 128*64; e += 256) {
        int c = e >> 6, j = e & 63;
        dst[e] = (c < C_) ? f2bf(sW[j*97 + c]) : (unsigned short)0;
    }
}

// ===========================================================================
// bf16 MFMA GEMM core (R6-verified)
// ===========================================================================
__device__ __forceinline__ void gemm128_core(const unsigned short* __restrict__ A,
                                             const unsigned short* __restrict__ Bt,
                                             int K, int row0, int col0,
                                             f4 (&acc)[4][4])
{
    __shared__ __attribute__((aligned(16))) unsigned short As[128][40];
    __shared__ __attribute__((aligned(16))) unsigned short Bs[128][40];
    int tid = threadIdx.x;
    int wave = tid >> 6, lane = tid & 63;
    int wr = wave & 1, wc = wave >> 1;
    int lm = lane & 15, quad = lane >> 4;

    for (int k0 = 0; k0 < K; k0 += 32) {
        #pragma unroll
        for (int s = 0; s < 2; ++s) {
            int ch = tid + s*256;
            int row = ch >> 2, part = ch & 3;
            *(ushort8*)&As[row][part*8] = *(const ushort8*)(A + (size_t)(row0 + row)*K + k0 + part*8);
            *(ushort8*)&Bs[row][part*8] = *(const ushort8*)(Bt + (size_t)(col0 + row)*K + k0 + part*8);
        }
        __syncthreads();
        s8 a[4], b[4];
        #pragma unroll
        for (int ti = 0; ti < 4; ++ti) a[ti] = *(const s8*)&As[wr*64 + ti*16 + lm][quad*8];
        #pragma unroll
        for (int tj = 0; tj < 4; ++tj) b[tj] = *(const s8*)&Bs[wc*64 + tj*16 + lm][quad*8];
        #pragma unroll
        for (int ti = 0; ti < 4; ++ti)
            #pragma unroll
            for (int tj = 0; tj < 4; ++tj)
                acc[ti][tj] = __builtin_amdgcn_mfma_f32_16x16x32_bf16(a[ti], b[tj], acc[ti][tj], 0, 0, 0);
        __syncthreads();
    }
}

// ===========================================================================
// Stage 3: rel GEMM (R6-verified)
// ===========================================================================
__global__ __launch_bounds__(256) void gemm_rel_mfma(const unsigned short* __restrict__ htA,
                                                     const unsigned short* __restrict__ seqT,
                                                     float* __restrict__ rel)
{
    int z = blockIdx.z;
    const unsigned short* A  = htA  + (size_t)z*R_*L_;
    const unsigned short* Bt = seqT + (size_t)z*H_*L_;
    float* C = rel + (size_t)z*R_*H_;
    int row0 = blockIdx.y*128, col0 = blockIdx.x*128;
    f4 acc[4][4] = {};
    gemm128_core(A, Bt, L_, row0, col0, acc);
    int lane = threadIdx.x & 63, wave = threadIdx.x >> 6;
    int wr = wave & 1, wc = wave >> 1, lm = lane & 15, quad = lane >> 4;
    #pragma unroll
    for (int ti = 0; ti < 4; ++ti)
        #pragma unroll
        for (int tj = 0; tj < 4; ++tj)
            #pragma unroll
            for (int r = 0; r < 4; ++r) {
                int row = row0 + wr*64 + ti*16 + quad*4 + r;
                int col = col0 + wc*64 + tj*16 + lm;
                C[(size_t)row*H_ + col] = acc[ti][tj][r];
            }
}

// ===========================================================================
// Stage 4: extractor GEMM (R6-verified, K=2048 single-bf16)
// ===========================================================================
__global__ __launch_bounds__(256) void gemm_ext_mfma(
    const unsigned short* __restrict__ Ah, const unsigned short* __restrict__ At,
    const unsigned short* __restrict__ WhT, const unsigned short* __restrict__ WtT,
    const float* __restrict__ bh, const float* __restrict__ bt,
    float* __restrict__ hv, float* __restrict__ tv)
{
    int z = blockIdx.z;
    const unsigned short* A  = z ? At  : Ah;
    const unsigned short* Bt = z ? WtT : WhT;
    const float* bias = z ? bt : bh;
    float* C = z ? tv : hv;
    int row0 = blockIdx.y*128, col0 = blockIdx.x*128;
    f4 acc[4][4] = {};
    gemm128_core(A, Bt, 2048, row0, col0, acc);
    int lane = threadIdx.x & 63, wave = threadIdx.x >> 6;
    int wr = wave & 1, wc = wave >> 1, lm = lane & 15, quad = lane >> 4;
    #pragma unroll
    for (int ti = 0; ti < 4; ++ti)
        #pragma unroll
        for (int tj = 0; tj < 4; ++tj)
            #pragma unroll
            for (int r = 0; r < 4; ++r) {
                int row = row0 + wr*64 + ti*16 + quad*4 + r;
                int col = col0 + wc*64 + tj*16 + lm;
                float x = acc[ti][tj][r] + bias[col];
                float e = __expf(2.f*x);
                C[(size_t)row*D_ + col] = 1.f - 2.f/(e + 1.f);   // tanh
            }
}

// ===========================================================================
// Stage 5a: init output with bias
// ===========================================================================
__global__ void out_init(const float* __restrict__ bb, float* __restrict__ out)
{
    int i = blockIdx.x*256 + threadIdx.x;
    if (i < NROW*C_) out[i] = bb[i % C_];
}

// ===========================================================================
// Stage 5b: block-bilinear classifier — R6-verified numeric path; ONLY change:
// Ws staging split into 8 unrolled independent global loads (issued BEFORE
// the barrier, overlapping previous iteration's compute) + 8 unrolled LDS
// writes after the barrier. Removes the per-chunk load->waitcnt->write
// serialization (~8 x L2 latency per iteration).
// ===========================================================================
__global__ __launch_bounds__(256) void final_mfma(
    const float* __restrict__ hv,             // [4096][768] f32
    const float* __restrict__ tv,
    const unsigned short* __restrict__ WbT,   // [12][64][128][64] bf16
    float* __restrict__ out)                  // [4096][97] f32
{
    int row0 = blockIdx.x * 64;
    int kb   = blockIdx.y;
    __shared__ __attribute__((aligned(16))) float hvS[64][68];
    __shared__ __attribute__((aligned(16))) float tvS[64][68];
    __shared__ __attribute__((aligned(16))) unsigned short Ws[2][128*64];

    int tid = threadIdx.x;
    // stage hv/tv kb-slices (64 rows x 64) as f32
    for (int e = tid; e < 1024; e += 256) {
        int r = e >> 4, part = e & 15;
        *(float4*)&hvS[r][part*4] = *(const float4*)(hv + (size_t)(row0 + r)*D_ + kb*BLK_ + part*4);
        *(float4*)&tvS[r][part*4] = *(const float4*)(tv + (size_t)(row0 + r)*D_ + kb*BLK_ + part*4);
    }
    int wave = tid >> 6, lane = tid & 63;
    int wr = wave & 1, wc = wave >> 1;
    int lm = lane & 15, quad = lane >> 4;
    __syncthreads();

    // preload tv fragments: constant across i within this kb
    float tvv[2][2][8];   // [rowtile][jhalf][t]
    #pragma unroll
    for (int rt = 0; rt < 2; ++rt)
        #pragma unroll
        for (int j2 = 0; j2 < 2; ++j2) {
            int r = wr*32 + rt*16 + lm;
            float4 p0 = *(const float4*)&tvS[r][j2*32 + quad*8];
            float4 p1 = *(const float4*)&tvS[r][j2*32 + quad*8 + 4];
            tvv[rt][j2][0]=p0.x; tvv[rt][j2][1]=p0.y; tvv[rt][j2][2]=p0.z; tvv[rt][j2][3]=p0.w;
            tvv[rt][j2][4]=p1.x; tvv[rt][j2][5]=p1.y; tvv[rt][j2][6]=p1.z; tvv[rt][j2][7]=p1.w;
        }

    f4 acc[2][4] = {};
    const unsigned short* wbase = WbT + (size_t)kb*64*128*64;

    // precompute per-thread staging indices (same mapping as R6)
    int swz_off[8];
    #pragma unroll
    for (int s = 0; s < 8; ++s) {
        int ch = tid + s*256;
        int ip = ch >> 10, rem = ch & 1023, c = rem >> 3, g = rem & 7;
        swz_off[s] = ip*(128*64) + c*64 + ((g ^ (c & 7))*8);
    }

    for (int i0 = 0; i0 < 64; i0 += 2) {
        // 8 independent loads first — latency overlaps previous iter's MFMAs
        ushort8 vbuf[8];
        #pragma unroll
        for (int s = 0; s < 8; ++s) {
            int ch = tid + s*256;
            int ip = ch >> 10, rem = ch & 1023, c = rem >> 3, g = rem & 7;
            vbuf[s] = *(const ushort8*)(wbase + (size_t)((i0 + ip)*128 + c)*64 + g*8);
        }
        __syncthreads();   // previous iteration's compute done; Ws reusable
        #pragma unroll
        for (int s = 0; s < 8; ++s)
            *(ushort8*)&Ws[0][swz_off[s]] = vbuf[s];
        __syncthreads();

        #pragma unroll
        for (int ip = 0; ip < 2; ++ip) {
            int i = i0 + ip;
            float sh0 = hvS[wr*32 + lm][i];
            float sh1 = hvS[wr*32 + 16 + lm][i];
            #pragma unroll
            for (int j2 = 0; j2 < 2; ++j2) {
                // build A-frags: bf16-truncate(sh * tvv) packed via v_perm
                s8 afr[2];
                #pragma unroll
                for (int rt = 0; rt < 2; ++rt) {
                    float sh = rt ? sh1 : sh0;
                    union { unsigned u[4]; s8 v; } cv;
                    #pragma unroll
                    for (int t2 = 0; t2 < 4; ++t2) {
                        float pe = sh * tvv[rt][j2][t2*2];
                        float po = sh * tvv[rt][j2][t2*2 + 1];
                        cv.u[t2] = __builtin_amdgcn_perm(__builtin_bit_cast(unsigned, po),
                                                         __builtin_bit_cast(unsigned, pe),
                                                         0x07060302u);
                    }
                    afr[rt] = cv.v;
                }
                #pragma unroll
                for (int ct = 0; ct < 4; ++ct) {
                    int c = wc*64 + ct*16 + lm;
                    int g = j2*4 + quad;
                    s8 bfr = *(const s8*)&Ws[ip][c*64 + ((g ^ (c & 7))*8)];
                    acc[0][ct] = __builtin_amdgcn_mfma_f32_16x16x32_bf16(afr[0], bfr, acc[0][ct], 0, 0, 0);
                    acc[1][ct] = __builtin_amdgcn_mfma_f32_16x16x32_bf16(afr[1], bfr, acc[1][ct], 0, 0, 0);
                }
            }
        }
    }

    #pragma unroll
    for (int rt = 0; rt < 2; ++rt)
        #pragma unroll
        for (int ct = 0; ct < 4; ++ct)
            #pragma unroll
            for (int r = 0; r < 4; ++r) {
                int row = row0 + wr*32 + rt*16 + quad*4 + r;
                int col = wc*64 + ct*16 + lm;
                if (col < C_) atomicAdd(out + (size_t)row*C_ + col, acc[rt][ct][r]);
            }
}

// ===========================================================================
extern "C" void kernel_launch(void* const* d_in, const int* in_sizes, int n_in,
                              void* d_out, int out_size, void* d_ws, size_t ws_size,
                              hipStream_t stream)
{
    const float* seq_lhs = (const float*)d_in[0];
    const float* ent_lhs = (const float*)d_in[1];
    const float* attn    = (const float*)d_in[2];
    const int*   labels  = (const int*)d_in[3];
    const int*   hts     = (const int*)d_in[4];
    const float* Wh      = (const float*)d_in[5];
    const float* bh      = (const float*)d_in[6];
    const float* Wt      = (const float*)d_in[7];
    const float* bt      = (const float*)d_in[8];
    const float* Wb      = (const float*)d_in[9];
    const float* bb      = (const float*)d_in[10];
    float* out = (float*)d_out;

    float* ws       = (float*)d_ws;
    float* ent_emb  = ws;                       // 262144 f32
    float* ent_attn = ent_emb  + 262144;        // 2097152
    float* ht_attn  = ent_attn + 2097152;       // 2097152
    float* rel      = ht_attn  + 2097152;       // 4194304
    float* hv       = rel      + 4194304;       // 3145728
    float* tv       = hv       + 3145728;       // 3145728
    unsigned short* htA  = (unsigned short*)(tv + 3145728); // 2097152 bf16
    unsigned short* seqT = htA  + 2097152;      // 2097152
    unsigned short* WhT  = seqT + 2097152;      // 1572864  (K=2048, no dup)
    unsigned short* WtT  = WhT  + 1572864;      // 1572864
    unsigned short* Ah   = WtT  + 1572864;      // 8388608  ([4096][2048])
    unsigned short* At   = Ah   + 8388608;      // 8388608
    unsigned short* WbT  = At   + 8388608;      // 6291456
    // total ~120.6 MB

    // weight preps (independent of activations)
    transpose_cvt_W<<<dim3(24, 64, 2), 256, 0, stream>>>(Wh, Wt, WhT, WtT);
    prep_WbT<<<KB_*64, 256, 0, stream>>>(Wb, WbT);
    transpose_cvt_seq<<<dim3(32, 16, B_), 256, 0, stream>>>(seq_lhs, seqT);

    pool_kernel<<<B_*E_, 256, 0, stream>>>(ent_lhs, attn, labels, ent_emb, ent_attn);
    pair_attn_kernel<<<B_*R_, 256, 0, stream>>>(ent_attn, hts, ht_attn);
    cvt_ht<<<1024, 256, 0, stream>>>(ht_attn, htA);
    gemm_rel_mfma<<<dim3(8, 8, B_), 256, 0, stream>>>(htA, seqT, rel);
    prep_hcat<<<NROW, 256, 0, stream>>>(ent_emb, rel, hts, Ah, At);
    gemm_ext_mfma<<<dim3(6, 32, 2), 256, 0, stream>>>(Ah, At, WhT, WtT, bh, bt, hv, tv);
    out_init<<<(NROW*C_ + 255)/256, 256, 0, stream>>>(bb, out);
    final_mfma<<<dim3(NROW/64, KB_), 256, 0, stream>>>(hv, tv, WbT, out);
}

// Round 8
// 370.152 us; speedup vs baseline: 6.2416x; 1.1111x over previous
//
#include <hip/hip_runtime.h>
#include <hip/hip_bf16.h>
#include <math.h>

// Problem constants
#define B_  4
#define L_  512
#define H_  1024
#define M_  128
#define E_  64
#define NH_ 16
#define R_  1024
#define D_  768
#define BLK_ 64
#define C_  97
#define NROW (B_*R_)          // 4096
#define KB_  (D_/BLK_)        // 12

typedef __attribute__((ext_vector_type(8))) unsigned short ushort8;
typedef __attribute__((ext_vector_type(4))) unsigned short ushort4v;
typedef __attribute__((ext_vector_type(8))) short s8;       // 8 bf16 MFMA operand
typedef __attribute__((ext_vector_type(4))) float f4;       // MFMA C/D

__device__ __forceinline__ unsigned short f2bf(float x) {   // RNE f32->bf16
    unsigned u = __builtin_bit_cast(unsigned, x);
    unsigned r = (u + 0x7fffu + ((u >> 16) & 1u)) >> 16;
    return (unsigned short)r;
}
__device__ __forceinline__ float bf2f(unsigned short h) {
    unsigned u = ((unsigned)h) << 16;
    return __builtin_bit_cast(float, u);
}
__device__ __forceinline__ float lo16f(unsigned u) { return __builtin_bit_cast(float, u << 16); }
__device__ __forceinline__ float hi16f(unsigned u) { return __builtin_bit_cast(float, u & 0xffff0000u); }

// ===========================================================================
// Stage 1: entity pooling -> bf16 outputs (R3 plumbing, exonerated)
// ===========================================================================
__global__ __launch_bounds__(256) void pool_kernel(
    const float* __restrict__ ent_lhs, const float* __restrict__ attn,
    const int* __restrict__ labels,
    unsigned short* __restrict__ ent_embB, unsigned short* __restrict__ ent_attnB)
{
    int be = blockIdx.x, b = be >> 6, e = be & 63;
    __shared__ int midx[M_];
    __shared__ int scnt;
    if (threadIdx.x == 0) scnt = 0;
    __syncthreads();
    if (threadIdx.x < M_) {
        if (labels[b*M_ + threadIdx.x] == e) {
            int p = atomicAdd(&scnt, 1);
            midx[p] = threadIdx.x;
        }
    }
    __syncthreads();
    int cnt = scnt;
    for (int h = threadIdx.x; h < H_; h += blockDim.x) {
        float r = 0.f;
        if (cnt > 0) {
            const float* base = ent_lhs + (size_t)b*M_*H_ + h;
            float mx = -INFINITY;
            for (int k = 0; k < cnt; ++k) mx = fmaxf(mx, base[(size_t)midx[k]*H_]);
            float s = 0.f;
            for (int k = 0; k < cnt; ++k) s += expf(base[(size_t)midx[k]*H_] - mx);
            r = mx + logf(s);
        }
        ent_embB[(size_t)be*H_ + h] = f2bf(r);
    }
    float inv = (cnt > 0) ? 1.f/(float)cnt : 0.f;
    for (int x = threadIdx.x; x < NH_*L_; x += blockDim.x) {
        int nh = x >> 9, l = x & (L_-1);
        const float* base = attn + (((size_t)b*NH_ + nh)*M_)*L_ + l;
        float s = 0.f;
        for (int k = 0; k < cnt; ++k) s += base[(size_t)midx[k]*L_];
        ent_attnB[((size_t)be*NH_ + nh)*L_ + l] = f2bf(s * inv);
    }
}

// ===========================================================================
// Stage 2: pair attention bf16 in -> bf16 htA directly (fuses old cvt_ht)
// ===========================================================================
__global__ __launch_bounds__(256) void pair_attn_kernel(
    const unsigned short* __restrict__ entA, const int* __restrict__ hts,
    unsigned short* __restrict__ htA)
{
    int br = blockIdx.x, b = br >> 10;
    int hi = hts[br*2 + 0], ti = hts[br*2 + 1];
    const unsigned* ph = (const unsigned*)(entA + ((size_t)(b*E_ + hi)*NH_)*L_);
    const unsigned* pt = (const unsigned*)(entA + ((size_t)(b*E_ + ti)*NH_)*L_);
    int l2 = threadIdx.x;                 // u32 index = pair of adjacent l's
    float v0 = 0.f, v1 = 0.f;
    #pragma unroll
    for (int nh = 0; nh < NH_; ++nh) {
        unsigned a = ph[nh*(L_/2) + l2], c = pt[nh*(L_/2) + l2];
        v0 += lo16f(a)*lo16f(c);
        v1 += hi16f(a)*hi16f(c);
    }
    float part = v0 + v1;
    __shared__ float red[4];
    #pragma unroll
    for (int off = 32; off > 0; off >>= 1) part += __shfl_down(part, off, 64);
    if ((threadIdx.x & 63) == 0) red[threadIdx.x >> 6] = part;
    __syncthreads();
    float total = red[0] + red[1] + red[2] + red[3];
    float norm = 1.f / (total*(1.f/16.f) + 1e-5f);   // denom on sum of nh-means
    unsigned short o0 = f2bf(v0*(1.f/16.f)*norm);
    unsigned short o1 = f2bf(v1*(1.f/16.f)*norm);
    *(unsigned*)(htA + (size_t)br*L_ + l2*2) = ((unsigned)o1 << 16) | o0;
}

// ===========================================================================
// Preps (R7-verified)
// ===========================================================================
__global__ __launch_bounds__(256) void transpose_cvt_seq(const float* __restrict__ in,
                                                         unsigned short* __restrict__ outp)
{
    int b = blockIdx.z;
    int h0 = blockIdx.x*32, l0 = blockIdx.y*32;
    __shared__ float tile[32][33];
    int tx = threadIdx.x & 31, ty = threadIdx.x >> 5;
    #pragma unroll
    for (int p = 0; p < 4; ++p)
        tile[ty + p*8][tx] = in[((size_t)b*L_ + l0 + ty + p*8)*H_ + h0 + tx];
    __syncthreads();
    #pragma unroll
    for (int p = 0; p < 4; ++p)
        outp[((size_t)b*H_ + h0 + ty + p*8)*L_ + l0 + tx] = f2bf(tile[tx][ty + p*8]);
}

__global__ __launch_bounds__(256) void transpose_cvt_W(const float* __restrict__ Wh,
                                                       const float* __restrict__ Wt,
                                                       unsigned short* __restrict__ WhT,
                                                       unsigned short* __restrict__ WtT)
{
    const float* in = blockIdx.z ? Wt : Wh;
    unsigned short* outp = blockIdx.z ? WtT : WhT;
    int n0 = blockIdx.x*32, k0 = blockIdx.y*32;
    __shared__ float tile[32][33];
    int tx = threadIdx.x & 31, ty = threadIdx.x >> 5;
    #pragma unroll
    for (int p = 0; p < 4; ++p)
        tile[ty + p*8][tx] = in[((size_t)(k0 + ty + p*8))*D_ + n0 + tx];
    __syncthreads();
    #pragma unroll
    for (int p = 0; p < 4; ++p) {
        int n = n0 + ty + p*8;
        outp[(size_t)n*2048 + k0 + tx] = f2bf(tile[tx][ty + p*8]);
    }
}

// gather ent rows (bf16 copy) into Ah/At cols [0,1024)  (R3 plumbing)
__global__ __launch_bounds__(256) void prep_gather(const unsigned short* __restrict__ entE,
                                                   const int* __restrict__ hts,
                                                   unsigned short* __restrict__ Ah,
                                                   unsigned short* __restrict__ At)
{
    int n = blockIdx.x, b = n >> 10;
    int m = threadIdx.x >> 7, off = (threadIdx.x & 127)*8;
    int idx = hts[n*2 + m];
    const unsigned short* src = entE + (size_t)(b*E_ + idx)*H_ + off;
    unsigned short* dst = (m ? At : Ah) + (size_t)n*2048 + off;
    *(ushort8*)dst = *(const ushort8*)src;
}

__global__ __launch_bounds__(256) void prep_WbT(const float* __restrict__ Wb,
                                                unsigned short* __restrict__ outp)
{
    int blk = blockIdx.x;                 // kb*64 + i
    __shared__ float sW[64*97];
    const float* src = Wb + (size_t)blk*64*97;
    for (int e = threadIdx.x; e < 64*97; e += 256) sW[e] = src[e];
    __syncthreads();
    unsigned short* dst = outp + (size_t)blk*128*64;
    for (int e = threadIdx.x; e < 128*64; e += 256) {
        int c = e >> 6, j = e & 63;
        dst[e] = (c < C_) ? f2bf(sW[j*97 + c]) : (unsigned short)0;
    }
}

// ===========================================================================
// bf16 MFMA GEMM core (R7-verified)
// ===========================================================================
__device__ __forceinline__ void gemm128_core(const unsigned short* __restrict__ A,
                                             const unsigned short* __restrict__ Bt,
                                             int K, int row0, int col0,
                                             f4 (&acc)[4][4])
{
    __shared__ __attribute__((aligned(16))) unsigned short As[128][40];
    __shared__ __attribute__((aligned(16))) unsigned short Bs[128][40];
    int tid = threadIdx.x;
    int wave = tid >> 6, lane = tid & 63;
    int wr = wave & 1, wc = wave >> 1;
    int lm = lane & 15, quad = lane >> 4;

    for (int k0 = 0; k0 < K; k0 += 32) {
        #pragma unroll
        for (int s = 0; s < 2; ++s) {
            int ch = tid + s*256;
            int row = ch >> 2, part = ch & 3;
            *(ushort8*)&As[row][part*8] = *(const ushort8*)(A + (size_t)(row0 + row)*K + k0 + part*8);
            *(ushort8*)&Bs[row][part*8] = *(const ushort8*)(Bt + (size_t)(col0 + row)*K + k0 + part*8);
        }
        __syncthreads();
        s8 a[4], b[4];
        #pragma unroll
        for (int ti = 0; ti < 4; ++ti) a[ti] = *(const s8*)&As[wr*64 + ti*16 + lm][quad*8];
        #pragma unroll
        for (int tj = 0; tj < 4; ++tj) b[tj] = *(const s8*)&Bs[wc*64 + tj*16 + lm][quad*8];
        #pragma unroll
        for (int ti = 0; ti < 4; ++ti)
            #pragma unroll
            for (int tj = 0; tj < 4; ++tj)
                acc[ti][tj] = __builtin_amdgcn_mfma_f32_16x16x32_bf16(a[ti], b[tj], acc[ti][tj], 0, 0, 0);
        __syncthreads();
    }
}

// ===========================================================================
// Stage 3: rel GEMM -> bf16 written directly into Ah/At cols [1024,2048)
// (R3 plumbing, exonerated; numerics identical to f32-roundtrip+f2bf)
// ===========================================================================
__global__ __launch_bounds__(256) void gemm_rel_mfma(const unsigned short* __restrict__ htA,
                                                     const unsigned short* __restrict__ seqT,
                                                     unsigned short* __restrict__ Ah,
                                                     unsigned short* __restrict__ At)
{
    int z = blockIdx.z;
    const unsigned short* A  = htA  + (size_t)z*R_*L_;
    const unsigned short* Bt = seqT + (size_t)z*H_*L_;
    int row0 = blockIdx.y*128, col0 = blockIdx.x*128;
    f4 acc[4][4] = {};
    gemm128_core(A, Bt, L_, row0, col0, acc);
    int lane = threadIdx.x & 63, wave = threadIdx.x >> 6;
    int wr = wave & 1, wc = wave >> 1, lm = lane & 15, quad = lane >> 4;
    #pragma unroll
    for (int ti = 0; ti < 4; ++ti)
        #pragma unroll
        for (int tj = 0; tj < 4; ++tj)
            #pragma unroll
            for (int r = 0; r < 4; ++r) {
                int n   = z*R_ + row0 + wr*64 + ti*16 + quad*4 + r;
                int col = col0 + wc*64 + tj*16 + lm;
                unsigned short v = f2bf(acc[ti][tj][r]);
                Ah[(size_t)n*2048 + 1024 + col] = v;
                At[(size_t)n*2048 + 1024 + col] = v;
            }
}

// ===========================================================================
// Stage 4: extractor GEMM (R7-verified, K=2048) + bias + tanh -> f32 hv/tv
// ===========================================================================
__global__ __launch_bounds__(256) void gemm_ext_mfma(
    const unsigned short* __restrict__ Ah, const unsigned short* __restrict__ At,
    const unsigned short* __restrict__ WhT, const unsigned short* __restrict__ WtT,
    const float* __restrict__ bh, const float* __restrict__ bt,
    float* __restrict__ hv, float* __restrict__ tv)
{
    int z = blockIdx.z;
    const unsigned short* A  = z ? At  : Ah;
    const unsigned short* Bt = z ? WtT : WhT;
    const float* bias = z ? bt : bh;
    float* C = z ? tv : hv;
    int row0 = blockIdx.y*128, col0 = blockIdx.x*128;
    f4 acc[4][4] = {};
    gemm128_core(A, Bt, 2048, row0, col0, acc);
    int lane = threadIdx.x & 63, wave = threadIdx.x >> 6;
    int wr = wave & 1, wc = wave >> 1, lm = lane & 15, quad = lane >> 4;
    #pragma unroll
    for (int ti = 0; ti < 4; ++ti)
        #pragma unroll
        for (int tj = 0; tj < 4; ++tj)
            #pragma unroll
            for (int r = 0; r < 4; ++r) {
                int row = row0 + wr*64 + ti*16 + quad*4 + r;
                int col = col0 + wc*64 + tj*16 + lm;
                float x = acc[ti][tj][r] + bias[col];
                float e = __expf(2.f*x);
                C[(size_t)row*D_ + col] = 1.f - 2.f/(e + 1.f);   // tanh
            }
}

// ===========================================================================
// Stage 5a: init output with bias
// ===========================================================================
__global__ void out_init(const float* __restrict__ bb, float* __restrict__ out)
{
    int i = blockIdx.x*256 + threadIdx.x;
    if (i < NROW*C_) out[i] = bb[i % C_];
}

// ===========================================================================
// Stage 5b: block-bilinear classifier — R7-verified structure + compute path
// (scalar pe/po, register-prefetch Ws). ONE change under test: hS/tS stored
// as bf16 in LDS (converted on stage). LDS 67584 -> 51200 B => 3 blocks/CU.
// ===========================================================================
__global__ __launch_bounds__(256) void final_mfma(
    const float* __restrict__ hv,             // [4096][768] f32
    const float* __restrict__ tv,
    const unsigned short* __restrict__ WbT,   // [12][64][128][64] bf16
    float* __restrict__ out)                  // [4096][97] f32
{
    int row0 = blockIdx.x * 64;
    int kb   = blockIdx.y;
    __shared__ __attribute__((aligned(16))) unsigned short hS[64][72];
    __shared__ __attribute__((aligned(16))) unsigned short tS[64][72];
    __shared__ __attribute__((aligned(16))) unsigned short Ws[2][128*64];

    int tid = threadIdx.x;
    // stage hv/tv kb-slices (64 rows x 64), f32 -> bf16 on the fly
    for (int e = tid; e < 1024; e += 256) {
        int r = e >> 4, part = e & 15;
        float4 xh = *(const float4*)(hv + (size_t)(row0 + r)*D_ + kb*BLK_ + part*4);
        float4 xt = *(const float4*)(tv + (size_t)(row0 + r)*D_ + kb*BLK_ + part*4);
        ushort4v ph = { f2bf(xh.x), f2bf(xh.y), f2bf(xh.z), f2bf(xh.w) };
        ushort4v pt = { f2bf(xt.x), f2bf(xt.y), f2bf(xt.z), f2bf(xt.w) };
        *(ushort4v*)&hS[r][part*4] = ph;
        *(ushort4v*)&tS[r][part*4] = pt;
    }
    int wave = tid >> 6, lane = tid & 63;
    int wr = wave & 1, wc = wave >> 1;
    int lm = lane & 15, quad = lane >> 4;
    __syncthreads();

    // preload tv fragments as scalar f32 (i-invariant within this kb)
    float tvv[2][2][8];   // [rowtile][jhalf][t]
    #pragma unroll
    for (int rt = 0; rt < 2; ++rt)
        #pragma unroll
        for (int j2 = 0; j2 < 2; ++j2) {
            int r = wr*32 + rt*16 + lm;
            ushort8 w = *(const ushort8*)&tS[r][j2*32 + quad*8];
            #pragma unroll
            for (int t = 0; t < 8; ++t) tvv[rt][j2][t] = bf2f(w[t]);
        }

    f4 acc[2][4] = {};
    const unsigned short* wbase = WbT + (size_t)kb*64*128*64;

    // precompute per-thread staging indices (R7-verified mapping)
    int swz_off[8];
    #pragma unroll
    for (int s = 0; s < 8; ++s) {
        int ch = tid + s*256;
        int ip = ch >> 10, rem = ch & 1023, c = rem >> 3, g = rem & 7;
        swz_off[s] = ip*(128*64) + c*64 + ((g ^ (c & 7))*8);
    }

    for (int i0 = 0; i0 < 64; i0 += 2) {
        // 8 independent loads first — latency overlaps previous iter's MFMAs
        ushort8 vbuf[8];
        #pragma unroll
        for (int s = 0; s < 8; ++s) {
            int ch = tid + s*256;
            int ip = ch >> 10, rem = ch & 1023, c = rem >> 3, g = rem & 7;
            vbuf[s] = *(const ushort8*)(wbase + (size_t)((i0 + ip)*128 + c)*64 + g*8);
        }
        __syncthreads();   // previous iteration's compute done; Ws reusable
        #pragma unroll
        for (int s = 0; s < 8; ++s)
            *(ushort8*)&Ws[0][swz_off[s]] = vbuf[s];
        __syncthreads();

        #pragma unroll
        for (int ip = 0; ip < 2; ++ip) {
            int i = i0 + ip;
            float sh0 = bf2f(hS[wr*32 + lm][i]);
            float sh1 = bf2f(hS[wr*32 + 16 + lm][i]);
            #pragma unroll
            for (int j2 = 0; j2 < 2; ++j2) {
                // build A-frags: bf16-truncate(sh * tvv) packed via v_perm
                s8 afr[2];
                #pragma unroll
                for (int rt = 0; rt < 2; ++rt) {
                    float sh = rt ? sh1 : sh0;
                    union { unsigned u[4]; s8 v; } cv;
                    #pragma unroll
                    for (int t2 = 0; t2 < 4; ++t2) {
                        float pe = sh * tvv[rt][j2][t2*2];
                        float po = sh * tvv[rt][j2][t2*2 + 1];
                        cv.u[t2] = __builtin_amdgcn_perm(__builtin_bit_cast(unsigned, po),
                                                         __builtin_bit_cast(unsigned, pe),
                                                         0x07060302u);
                    }
                    afr[rt] = cv.v;
                }
                #pragma unroll
                for (int ct = 0; ct < 4; ++ct) {
                    int c = wc*64 + ct*16 + lm;
                    int g = j2*4 + quad;
                    s8 bfr = *(const s8*)&Ws[ip][c*64 + ((g ^ (c & 7))*8)];
                    acc[0][ct] = __builtin_amdgcn_mfma_f32_16x16x32_bf16(afr[0], bfr, acc[0][ct], 0, 0, 0);
                    acc[1][ct] = __builtin_amdgcn_mfma_f32_16x16x32_bf16(afr[1], bfr, acc[1][ct], 0, 0, 0);
                }
            }
        }
    }

    #pragma unroll
    for (int rt = 0; rt < 2; ++rt)
        #pragma unroll
        for (int ct = 0; ct < 4; ++ct)
            #pragma unroll
            for (int r = 0; r < 4; ++r) {
                int row = row0 + wr*32 + rt*16 + quad*4 + r;
                int col = wc*64 + ct*16 + lm;
                if (col < C_) atomicAdd(out + (size_t)row*C_ + col, acc[rt][ct][r]);
            }
}

// ===========================================================================
extern "C" void kernel_launch(void* const* d_in, const int* in_sizes, int n_in,
                              void* d_out, int out_size, void* d_ws, size_t ws_size,
                              hipStream_t stream)
{
    const float* seq_lhs = (const float*)d_in[0];
    const float* ent_lhs = (const float*)d_in[1];
    const float* attn    = (const float*)d_in[2];
    const int*   labels  = (const int*)d_in[3];
    const int*   hts     = (const int*)d_in[4];
    const float* Wh      = (const float*)d_in[5];
    const float* bh      = (const float*)d_in[6];
    const float* Wt      = (const float*)d_in[7];
    const float* bt      = (const float*)d_in[8];
    const float* Wb      = (const float*)d_in[9];
    const float* bb      = (const float*)d_in[10];
    float* out = (float*)d_out;

    float* wsf      = (float*)d_ws;
    float* hv       = wsf;                       // 3145728 f32
    float* tv       = hv + 3145728;              // 3145728 f32
    unsigned short* ent_embB  = (unsigned short*)(tv + 3145728); // 262144
    unsigned short* ent_attnB = ent_embB  + 262144;   // 2097152
    unsigned short* htA       = ent_attnB + 2097152;  // 2097152
    unsigned short* seqT      = htA       + 2097152;  // 2097152
    unsigned short* WhT       = seqT      + 2097152;  // 1572864
    unsigned short* WtT       = WhT       + 1572864;  // 1572864
    unsigned short* Ah        = WtT       + 1572864;  // 8388608 ([4096][2048])
    unsigned short* At        = Ah        + 8388608;  // 8388608
    unsigned short* WbT       = At        + 8388608;  // 6291456
    // total ~90.4 MB

    // weight preps (independent of activations)
    transpose_cvt_W<<<dim3(24, 64, 2), 256, 0, stream>>>(Wh, Wt, WhT, WtT);
    prep_WbT<<<KB_*64, 256, 0, stream>>>(Wb, WbT);
    transpose_cvt_seq<<<dim3(32, 16, B_), 256, 0, stream>>>(seq_lhs, seqT);

    pool_kernel<<<B_*E_, 256, 0, stream>>>(ent_lhs, attn, labels, ent_embB, ent_attnB);
    pair_attn_kernel<<<B_*R_, 256, 0, stream>>>(ent_attnB, hts, htA);
    gemm_rel_mfma<<<dim3(8, 8, B_), 256, 0, stream>>>(htA, seqT, Ah, At);
    prep_gather<<<NROW, 256, 0, stream>>>(ent_embB, hts, Ah, At);
    gemm_ext_mfma<<<dim3(6, 32, 2), 256, 0, stream>>>(Ah, At, WhT, WtT, bh, bt, hv, tv);
    out_init<<<(NROW*C_ + 255)/256, 256, 0, stream>>>(bb, out);
    final_mfma<<<dim3(NROW/64, KB_), 256, 0, stream>>>(hv, tv, WbT, out);
}